// Round 9
// baseline (328.641 us; speedup 1.0000x reference)
//
#include <hip/hip_runtime.h>
#include <hip/hip_bf16.h>
#include <hip/hip_cooperative_groups.h>

namespace cg = cooperative_groups;

// RGCN layer: out = relu( segment_sum(blockdiag_msg) * norm + h @ loop_weight )
//
// Inputs (setup_inputs order):
//   0: h           [N,128]  f32
//   1: norm        [N,1]    f32
//   2: weight      [R,1024] f32   (R x NB(16) x SI(8) x SO(8))
//   3: loop_weight [128,128] f32
//   4: src         [E] i32
//   5: dst         [E] i32
//   6: etype       [E] i32
// Output: [N,128] f32
//
// Round-8: agg is at its L2-gather floor (~58us; r4/r5/r6/r7 bracket it).
// The other ~90us is ~35us of work + ~55us of dispatch gaps (6 launches).
// Fuse the whole prologue (zero+pack+hist+gemm+offsets+scatter) into ONE
// cooperative kernel with 3 grid.sync()s; agg stays a separate dispatch
// (keeps its own occupancy). offsets now self-computes its chunk prefix
// from cnt (chunksum/bsum dropped). Fallback r7 path kept if coop absent.

#define IN_FEAT 128
#define OUT_FEAT 128
#define SCAN_CHUNK 512

using short8  = __attribute__((ext_vector_type(8))) short;
using float4v = __attribute__((ext_vector_type(4))) float;

__device__ inline float blo(unsigned u) { return __uint_as_float(u << 16); }
__device__ inline float bhi(unsigned u) { return __uint_as_float(u & 0xffff0000u); }
__device__ inline unsigned short f2bf(float f) {
  __hip_bfloat16 b = __float2bfloat16(f);
  return *reinterpret_cast<unsigned short*>(&b);
}

// dword = 2 packed bf16; returns c + x.lo*w.lo + x.hi*w.hi
__device__ inline float dot2bf(unsigned x, unsigned w, float c) {
#if __has_builtin(__builtin_amdgcn_fdot2_f32_bf16)
  typedef __bf16 bf16x2 __attribute__((ext_vector_type(2)));
  return __builtin_amdgcn_fdot2_f32_bf16(__builtin_bit_cast(bf16x2, x),
                                         __builtin_bit_cast(bf16x2, w), c, false);
#else
  return c + blo(x) * blo(w) + bhi(x) * bhi(w);
#endif
}

// ---------------------------------------------------------------------------
// Cooperative pipeline: one dispatch replaces memset+k_prep+k_gemm_sum+
// k_offsets+k_scatter. Phases separated by grid.sync():
//   A: cnt=0 | w16 pack | h16 pack | lwT pack       (elementwise grid-stride)
//   B: self-loop MFMA GEMM (out=loop_message) | hist (atomics on cnt)
//   C: per-chunk exclusive scan -> pos, chunk prefix summed directly from cnt
//   D: scatter edges into dst-sorted srcet (pos -> segment END)
// No early returns (all threads reach all syncs); all loops grid-stride.
// ---------------------------------------------------------------------------
__global__ __launch_bounds__(256, 4) void k_pipeline(
    const float* __restrict__ w, const float* __restrict__ h,
    const float* __restrict__ lw, const int* __restrict__ src,
    const int* __restrict__ dst, const int* __restrict__ etype,
    unsigned short* __restrict__ w16, uint4* __restrict__ h16p,
    unsigned short* __restrict__ lwT, int* __restrict__ cnt,
    int* __restrict__ pos, int2* __restrict__ srcet,
    float* __restrict__ out, int N, int E, int R) {
  cg::grid_group grid = cg::this_grid();
  const int nb = (int)gridDim.x;
  const int tid = (int)threadIdx.x;
  const int gtid = (int)blockIdx.x * 256 + tid;
  const int gstride = nb * 256;

  // ---------------- Phase A ----------------
  for (int i = gtid; i < N; i += gstride) cnt[i] = 0;

  const int wtotal = R * 1024;
  for (int idx = gtid; idx < wtotal; idx += gstride) {
    const int r = idx >> 10;
    const int rem = idx & 1023;
    const int b = rem >> 6;
    const int q = rem & 63;
    const int opp = q >> 4;
    const int t = q & 15;
    const int j = t >> 3;
    const int i = t & 7;
    w16[idx] = f2bf(w[((size_t)r << 10) + b * 64 + i * 8 + opp * 2 + j]);
  }

  const int htotal8 = N * (IN_FEAT / 8);
  for (int t8 = gtid; t8 < htotal8; t8 += gstride) {
    const float4 a = ((const float4*)h)[2 * t8];
    const float4 b = ((const float4*)h)[2 * t8 + 1];
    uint4 o;
    o.x = (unsigned)f2bf(a.x) | ((unsigned)f2bf(a.y) << 16);
    o.y = (unsigned)f2bf(a.z) | ((unsigned)f2bf(a.w) << 16);
    o.z = (unsigned)f2bf(b.x) | ((unsigned)f2bf(b.y) << 16);
    o.w = (unsigned)f2bf(b.z) | ((unsigned)f2bf(b.w) << 16);
    h16p[t8] = o;
  }

  for (int idx = gtid; idx < IN_FEAT * OUT_FEAT; idx += gstride) {
    const int o = idx >> 7;
    const int k = idx & 127;
    lwT[idx] = f2bf(lw[k * 128 + o]);
  }

  grid.sync();

  // ---------------- Phase B: GEMM + hist ----------------
  {
    const unsigned short* h16 = (const unsigned short*)h16p;
    const int wid = tid >> 6;
    const int lane = tid & 63;
    const int m = lane & 15;
    const int kg = (lane >> 4) * 8;
    const int gemm_vb = (N + 63) >> 6;
    for (int vb = (int)blockIdx.x; vb < gemm_vb; vb += nb) {
      const int row0 = vb * 64 + wid * 16;
      if (row0 < N) {
        const int arow = min(row0 + m, N - 1);
        float4v acc[8];
        #pragma unroll
        for (int nt = 0; nt < 8; ++nt) acc[nt] = (float4v){0.f, 0.f, 0.f, 0.f};
        const unsigned short* ap = h16 + (size_t)arow * 128 + kg;
        const unsigned short* bp = lwT + (size_t)m * 128 + kg;
        #pragma unroll
        for (int kc = 0; kc < 4; ++kc) {
          const short8 a = *(const short8*)(ap + kc * 32);
          #pragma unroll
          for (int nt = 0; nt < 8; ++nt) {
            const short8 b = *(const short8*)(bp + nt * 2048 + kc * 32);
            acc[nt] =
                __builtin_amdgcn_mfma_f32_16x16x32_bf16(a, b, acc[nt], 0, 0, 0);
          }
        }
        const int crow = row0 + (lane >> 4) * 4;
        #pragma unroll
        for (int nt = 0; nt < 8; ++nt) {
          #pragma unroll
          for (int r = 0; r < 4; ++r) {
            const int row = crow + r;
            if (row < N) out[(size_t)row * 128 + nt * 16 + m] = acc[nt][r];
          }
        }
      }
    }
  }
  {
    const int e4 = (E + 3) >> 2;
    for (int g = gtid; g < e4; g += gstride) {
      const int e0 = g * 4;
      if (e0 + 3 < E) {
        const int4 d4 = *(const int4*)(dst + e0);
        atomicAdd(&cnt[d4.x], 1);
        atomicAdd(&cnt[d4.y], 1);
        atomicAdd(&cnt[d4.z], 1);
        atomicAdd(&cnt[d4.w], 1);
      } else {
        for (int e = e0; e < E; ++e) atomicAdd(&cnt[dst[e]], 1);
      }
    }
  }

  grid.sync();

  // ---------------- Phase C: offsets (self prefix) ----------------
  {
    __shared__ int s[256];
    __shared__ int sbase;
    const int nblk = (N + SCAN_CHUNK - 1) / SCAN_CHUNK;
    for (int vb = (int)blockIdx.x; vb < nblk; vb += nb) {
      __syncthreads();  // guard LDS reuse across vb iterations
      // chunk prefix = sum cnt[0 .. vb*512)
      const int lim = vb * SCAN_CHUNK;
      int acc = 0;
      for (int i = tid; i < lim; i += 256) acc += cnt[i];
      s[tid] = acc;
      __syncthreads();
      for (int d = 128; d > 0; d >>= 1) {
        if (tid < d) s[tid] += s[tid + d];
        __syncthreads();
      }
      if (tid == 0) sbase = s[0];
      __syncthreads();
      // exclusive scan of this chunk
      const int base = vb * SCAN_CHUNK;
      const int i0 = base + 2 * tid;
      const int i1 = i0 + 1;
      const int c0 = (i0 < N) ? cnt[i0] : 0;
      const int c1 = (i1 < N) ? cnt[i1] : 0;
      const int pair = c0 + c1;
      s[tid] = pair;
      __syncthreads();
      #pragma unroll
      for (int d = 1; d < 256; d <<= 1) {
        int v = (tid >= d) ? s[tid - d] : 0;
        __syncthreads();
        s[tid] += v;
        __syncthreads();
      }
      const int ex = s[tid] - pair + sbase;
      if (i0 < N) pos[i0] = ex;
      if (i1 < N) pos[i1] = ex + c0;
    }
  }

  grid.sync();

  // ---------------- Phase D: scatter ----------------
  {
    const int e4 = (E + 3) >> 2;
    for (int g = gtid; g < e4; g += gstride) {
      const int e0 = g * 4;
      if (e0 + 3 < E) {
        const int4 s4 = *(const int4*)(src + e0);
        const int4 d4 = *(const int4*)(dst + e0);
        const int4 t4 = *(const int4*)(etype + e0);
        int p;
        p = atomicAdd(&pos[d4.x], 1); srcet[p] = make_int2(s4.x, t4.x);
        p = atomicAdd(&pos[d4.y], 1); srcet[p] = make_int2(s4.y, t4.y);
        p = atomicAdd(&pos[d4.z], 1); srcet[p] = make_int2(s4.z, t4.z);
        p = atomicAdd(&pos[d4.w], 1); srcet[p] = make_int2(s4.w, t4.w);
      } else {
        for (int e = e0; e < E; ++e) {
          const int p = atomicAdd(&pos[dst[e]], 1);
          srcet[p] = make_int2(src[e], etype[e]);
        }
      }
    }
  }
}

// ---------------------------------------------------------------------------
// bf16 aggregation (round-7 proven form): one wave per node; lane (b,opp)
// owns outputs o=b*8+opp*2, o+1. Per 4-edge group one 16B load fetches all
// 4 edges' h rows (lane=(edge,chunk)), distributed via shfl; per edge
// 2 x 16B weight loads + 8 dot2. Epilogue prev/norm prefetched.
// out = relu(out + acc*norm)   (out holds loop_message).
// ---------------------------------------------------------------------------
__global__ __launch_bounds__(256) void agg_bf16(
    const unsigned short* __restrict__ h16, const float* __restrict__ norm,
    const unsigned short* __restrict__ w16, const int* __restrict__ pos,
    const int* __restrict__ cnt, const int2* __restrict__ srcet,
    float* __restrict__ out, int N) {
  const int node = (int)((blockIdx.x * blockDim.x + threadIdx.x) >> 6);
  const int lane = threadIdx.x & 63;
  if (node >= N) return;

  const int b = lane >> 2;
  const int opp = lane & 3;
  const int woff = b * 64 + opp * 16;  // ushort units
  const int o = b * 8 + opp * 2;

  const int num = cnt[node];
  const int end = pos[node];
  const int begin = end - num;

  float* outp = out + ((size_t)node << 7) + o;
  const float2 prev = *(const float2*)outp;
  const float nm = norm[node];

  float a0 = 0.f, a1 = 0.f;

  for (int base = 0; base < num; base += 64) {
    const int cn = min(64, num - base);
    const int2 my = srcet[begin + base + min(lane, cn - 1)];
    for (int i4 = 0; i4 < cn; i4 += 4) {
      const int gl = min(i4 + (lane >> 4), cn - 1);
      const int sg = __shfl(my.x, gl);
      const uint4 xq =
          *(const uint4*)(h16 + ((size_t)sg << 7) + (lane & 15) * 8);
      const int nin = min(4, cn - i4);
      #pragma unroll 4
      for (int u = 0; u < nin; ++u) {
        const int r = __shfl(my.y, i4 + u);
        const int sl = u * 16 + b;
        uint4 xv;
        xv.x = __shfl(xq.x, sl);
        xv.y = __shfl(xq.y, sl);
        xv.z = __shfl(xq.z, sl);
        xv.w = __shfl(xq.w, sl);
        const unsigned short* wp = w16 + ((size_t)r << 10) + woff;
        const uint4 wa = *(const uint4*)(wp);
        const uint4 wb = *(const uint4*)(wp + 8);

        a0 = dot2bf(xv.x, wa.x, a0);
        a0 = dot2bf(xv.y, wa.y, a0);
        a0 = dot2bf(xv.z, wa.z, a0);
        a0 = dot2bf(xv.w, wa.w, a0);
        a1 = dot2bf(xv.x, wb.x, a1);
        a1 = dot2bf(xv.y, wb.y, a1);
        a1 = dot2bf(xv.z, wb.z, a1);
        a1 = dot2bf(xv.w, wb.w, a1);
      }
    }
  }

  float2 res;
  res.x = fmaxf(prev.x + a0 * nm, 0.f);
  res.y = fmaxf(prev.y + a1 * nm, 0.f);
  *(float2*)outp = res;
}

// ===========================================================================
// Non-cooperative fallback kernels (round-7 path)
// ===========================================================================
__global__ __launch_bounds__(256) void k_prep(
    const float* __restrict__ w, unsigned short* __restrict__ w16,
    const float* __restrict__ h, uint4* __restrict__ h16p, int htotal8,
    const float* __restrict__ lw, unsigned short* __restrict__ lwT,
    const int* __restrict__ dst, int* __restrict__ cnt, int E,
    int bw, int bh, int blw) {
  __shared__ float srow[1024];
  const int bid = blockIdx.x;
  if (bid < bw) {  // bw == R; one relation per block
    const float* wr = w + ((size_t)bid << 10);
    ((float4*)srow)[threadIdx.x] = ((const float4*)wr)[threadIdx.x];
    __syncthreads();
    const int d0 = threadIdx.x * 4;
    unsigned short o4[4];
    #pragma unroll
    for (int k = 0; k < 4; ++k) {
      const int d = d0 + k;
      const int b = d >> 6;
      const int q = d & 63;
      const int opp = q >> 4;
      const int tt = q & 15;
      const int jj = tt >> 3;
      const int ii = tt & 7;
      o4[k] = f2bf(srow[b * 64 + ii * 8 + opp * 2 + jj]);
    }
    *(uint2*)(w16 + ((size_t)bid << 10) + d0) =
        make_uint2((unsigned)o4[0] | ((unsigned)o4[1] << 16),
                   (unsigned)o4[2] | ((unsigned)o4[3] << 16));
  } else if (bid < bw + bh) {
    const int t = (bid - bw) * 256 + threadIdx.x;
    if (t < htotal8) {
      const float4 a = ((const float4*)h)[2 * t];
      const float4 b = ((const float4*)h)[2 * t + 1];
      uint4 o;
      o.x = (unsigned)f2bf(a.x) | ((unsigned)f2bf(a.y) << 16);
      o.y = (unsigned)f2bf(a.z) | ((unsigned)f2bf(a.w) << 16);
      o.z = (unsigned)f2bf(b.x) | ((unsigned)f2bf(b.y) << 16);
      o.w = (unsigned)f2bf(b.z) | ((unsigned)f2bf(b.w) << 16);
      h16p[t] = o;
    }
  } else if (bid < bw + bh + blw) {
    const int idx = (bid - bw - bh) * 256 + threadIdx.x;
    if (idx < IN_FEAT * OUT_FEAT) {
      const int o = idx >> 7;
      const int k = idx & 127;
      lwT[idx] = f2bf(lw[k * 128 + o]);
    }
  } else {
    const int e0 = ((bid - bw - bh - blw) * 256 + threadIdx.x) * 4;
    if (e0 + 3 < E) {
      const int4 d4 = *(const int4*)(dst + e0);
      atomicAdd(&cnt[d4.x], 1);
      atomicAdd(&cnt[d4.y], 1);
      atomicAdd(&cnt[d4.z], 1);
      atomicAdd(&cnt[d4.w], 1);
    } else {
      for (int e = e0; e < E; ++e) atomicAdd(&cnt[dst[e]], 1);
    }
  }
}

__global__ __launch_bounds__(256) void k_gemm_sum(
    const unsigned short* __restrict__ h16, const unsigned short* __restrict__ lwT,
    float* __restrict__ out, int N,
    const int* __restrict__ cnt, int* __restrict__ bsum, int gemm_blocks) {
  if (blockIdx.x < gemm_blocks) {
    const int wid = threadIdx.x >> 6;
    const int lane = threadIdx.x & 63;
    const int row0 = blockIdx.x * 64 + wid * 16;
    if (row0 >= N) return;
    const int m = lane & 15;
    const int kg = (lane >> 4) * 8;
    const int arow = min(row0 + m, N - 1);

    float4v acc[8];
    #pragma unroll
    for (int nt = 0; nt < 8; ++nt) acc[nt] = (float4v){0.f, 0.f, 0.f, 0.f};

    const unsigned short* ap = h16 + (size_t)arow * 128 + kg;
    const unsigned short* bp = lwT + (size_t)m * 128 + kg;

    #pragma unroll
    for (int kc = 0; kc < 4; ++kc) {
      const short8 a = *(const short8*)(ap + kc * 32);
      #pragma unroll
      for (int nt = 0; nt < 8; ++nt) {
        const short8 b = *(const short8*)(bp + nt * 2048 + kc * 32);
        acc[nt] = __builtin_amdgcn_mfma_f32_16x16x32_bf16(a, b, acc[nt], 0, 0, 0);
      }
    }

    const int crow = row0 + (lane >> 4) * 4;
    #pragma unroll
    for (int nt = 0; nt < 8; ++nt) {
      #pragma unroll
      for (int r = 0; r < 4; ++r) {
        const int row = crow + r;
        if (row < N) out[(size_t)row * 128 + nt * 16 + m] = acc[nt][r];
      }
    }
  } else {
    __shared__ int s[256];
    const int cb = blockIdx.x - gemm_blocks;
    const int t = threadIdx.x;
    const int base = cb * SCAN_CHUNK;
    int v = 0;
    const int i0 = base + t, i1 = base + 256 + t;
    if (i0 < N) v += cnt[i0];
    if (i1 < N) v += cnt[i1];
    s[t] = v;
    __syncthreads();
    for (int d = 128; d > 0; d >>= 1) {
      if (t < d) s[t] += s[t + d];
      __syncthreads();
    }
    if (t == 0) bsum[cb] = s[0];
  }
}

__global__ __launch_bounds__(256) void k_offsets(
    const int* __restrict__ cnt, const int* __restrict__ bsum,
    int* __restrict__ pos, int N) {
  __shared__ int s[256];
  __shared__ int sbase;
  const int t = threadIdx.x;
  if (t < 64) {
    int acc = 0;
    for (int j = t; j < (int)blockIdx.x; j += 64) acc += bsum[j];
    #pragma unroll
    for (int d = 1; d < 64; d <<= 1) acc += __shfl_xor(acc, d);
    if (t == 0) sbase = acc;
  }
  const int base = blockIdx.x * SCAN_CHUNK;
  const int i0 = base + 2 * t;
  const int i1 = i0 + 1;
  const int c0 = (i0 < N) ? cnt[i0] : 0;
  const int c1 = (i1 < N) ? cnt[i1] : 0;
  const int pair = c0 + c1;
  s[t] = pair;
  __syncthreads();
  #pragma unroll
  for (int d = 1; d < 256; d <<= 1) {
    int v = (t >= d) ? s[t - d] : 0;
    __syncthreads();
    s[t] += v;
    __syncthreads();
  }
  const int ex = s[t] - pair + sbase;
  if (i0 < N) pos[i0] = ex;
  if (i1 < N) pos[i1] = ex + c0;
}

__global__ __launch_bounds__(256) void k_scatter(
    const int* __restrict__ src, const int* __restrict__ dst,
    const int* __restrict__ etype, int* __restrict__ pos,
    int2* __restrict__ srcet, int E) {
  const int e0 = (blockIdx.x * blockDim.x + threadIdx.x) * 4;
  if (e0 + 3 < E) {
    const int4 s4 = *(const int4*)(src + e0);
    const int4 d4 = *(const int4*)(dst + e0);
    const int4 t4 = *(const int4*)(etype + e0);
    int p;
    p = atomicAdd(&pos[d4.x], 1); srcet[p] = make_int2(s4.x, t4.x);
    p = atomicAdd(&pos[d4.y], 1); srcet[p] = make_int2(s4.y, t4.y);
    p = atomicAdd(&pos[d4.z], 1); srcet[p] = make_int2(s4.z, t4.z);
    p = atomicAdd(&pos[d4.w], 1); srcet[p] = make_int2(s4.w, t4.w);
  } else {
    for (int e = e0; e < E; ++e) {
      const int p = atomicAdd(&pos[dst[e]], 1);
      srcet[p] = make_int2(src[e], etype[e]);
    }
  }
}

__global__ __launch_bounds__(256) void k_hist(
    const int* __restrict__ dst, int* __restrict__ cnt, int E) {
  const int e = blockIdx.x * blockDim.x + threadIdx.x;
  if (e < E) atomicAdd(&cnt[dst[e]], 1);
}

__global__ __launch_bounds__(256) void k_chunksum(
    const int* __restrict__ cnt, int* __restrict__ bsum, int N) {
  __shared__ int s[256];
  const int t = threadIdx.x;
  const int base = blockIdx.x * SCAN_CHUNK;
  int v = 0;
  int i0 = base + t, i1 = base + 256 + t;
  if (i0 < N) v += cnt[i0];
  if (i1 < N) v += cnt[i1];
  s[t] = v;
  __syncthreads();
  for (int d = 128; d > 0; d >>= 1) {
    if (t < d) s[t] += s[t + d];
    __syncthreads();
  }
  if (t == 0) bsum[blockIdx.x] = s[0];
}

__global__ __launch_bounds__(256) void selfloop_gemm(
    const float* __restrict__ h, const float* __restrict__ lw,
    float* __restrict__ out, int n) {
  __shared__ float slw[IN_FEAT * OUT_FEAT];
  __shared__ float sh[32 * IN_FEAT];

  {
    const float4* s4 = (const float4*)lw;
    float4* d4 = (float4*)slw;
    for (int i = threadIdx.x; i < IN_FEAT * OUT_FEAT / 4; i += 256) d4[i] = s4[i];
  }

  const int cg_ = threadIdx.x & 31;
  const int rg = threadIdx.x >> 5;

  for (int base = blockIdx.x * 32; base < n; base += gridDim.x * 32) {
    const int nrows = min(32, n - base);
    __syncthreads();
    {
      const float4* hs = (const float4*)(h + (size_t)base * IN_FEAT);
      float4* sd = (float4*)sh;
      const int cnt = nrows * (IN_FEAT / 4);
      for (int i = threadIdx.x; i < cnt; i += 256) sd[i] = hs[i];
    }
    __syncthreads();

    float4 acc[4];
    #pragma unroll
    for (int j = 0; j < 4; ++j) acc[j] = make_float4(0.f, 0.f, 0.f, 0.f);

    #pragma unroll 4
    for (int k = 0; k < IN_FEAT; ++k) {
      const float4 w = ((const float4*)slw)[k * 32 + cg_];
      #pragma unroll
      for (int j = 0; j < 4; ++j) {
        const float hv = sh[(rg + 8 * j) * IN_FEAT + k];
        acc[j].x += hv * w.x;
        acc[j].y += hv * w.y;
        acc[j].z += hv * w.z;
        acc[j].w += hv * w.w;
      }
    }

    #pragma unroll
    for (int j = 0; j < 4; ++j) {
      const int r = rg + 8 * j;
      if (r < nrows) {
        ((float4*)(out + (size_t)(base + r) * OUT_FEAT))[cg_] = acc[j];
      }
    }
  }
}

__global__ __launch_bounds__(256) void agg(
    const float* __restrict__ h, const float* __restrict__ norm,
    const float* __restrict__ weight, const int* __restrict__ pos,
    const int* __restrict__ cnt, const int2* __restrict__ srcet,
    float* __restrict__ out, int N) {
  const int node = (int)((blockIdx.x * blockDim.x + threadIdx.x) >> 6);
  const int lane = threadIdx.x & 63;
  if (node >= N) return;

  const int b = lane >> 2;
  const int op = (lane & 3) * 2;
  const int boff = b * 64 + op;

  const int num = cnt[node];
  const int end = pos[node];
  const int begin = end - num;

  float a0 = 0.f, a1 = 0.f;

  for (int base = 0; base < num; base += 64) {
    const int cn = min(64, num - base);
    const int2 my = srcet[begin + base + min(lane, cn - 1)];
    #pragma unroll 2
    for (int i = 0; i < cn; ++i) {
      const int s = __shfl(my.x, i);
      const int r = __shfl(my.y, i);
      const float* xp = h + ((size_t)s << 7) + b * 8;
      const float4 x0 = ((const float4*)xp)[0];
      const float4 x1 = ((const float4*)xp)[1];
      const float* wp = weight + ((size_t)r << 10) + boff;
      const float2 w0 = *(const float2*)(wp);
      const float2 w1 = *(const float2*)(wp + 8);
      const float2 w2 = *(const float2*)(wp + 16);
      const float2 w3 = *(const float2*)(wp + 24);
      const float2 w4 = *(const float2*)(wp + 32);
      const float2 w5 = *(const float2*)(wp + 40);
      const float2 w6 = *(const float2*)(wp + 48);
      const float2 w7 = *(const float2*)(wp + 56);
      a0 += x0.x * w0.x; a1 += x0.x * w0.y;
      a0 += x0.y * w1.x; a1 += x0.y * w1.y;
      a0 += x0.z * w2.x; a1 += x0.z * w2.y;
      a0 += x0.w * w3.x; a1 += x0.w * w3.y;
      a0 += x1.x * w4.x; a1 += x1.x * w4.y;
      a0 += x1.y * w5.x; a1 += x1.y * w5.y;
      a0 += x1.z * w6.x; a1 += x1.z * w6.y;
      a0 += x1.w * w7.x; a1 += x1.w * w7.y;
    }
  }

  const float nm = norm[node];
  const int o = b * 8 + op;
  float* outp = out + ((size_t)node << 7) + o;
  float2 prev = *(const float2*)outp;
  float2 res;
  res.x = fmaxf(prev.x + a0 * nm, 0.f);
  res.y = fmaxf(prev.y + a1 * nm, 0.f);
  *(float2*)outp = res;
}

__global__ __launch_bounds__(256) void edge_msg(
    const float* __restrict__ h, const float* __restrict__ norm,
    const float* __restrict__ weight, const int* __restrict__ src,
    const int* __restrict__ dst, const int* __restrict__ etype,
    float* out, int E) {
  const int wave = (int)((blockIdx.x * blockDim.x + threadIdx.x) >> 6);
  const int lane = threadIdx.x & 63;
  if (wave >= E) return;

  const int s = src[wave];
  const int d = dst[wave];
  const int r = etype[wave];
  const float nrm = norm[d];

  const int b = lane >> 2;
  const int op = (lane & 3) * 2;

  const float* xp = h + (size_t)s * IN_FEAT + b * 8;
  const float4 x0 = ((const float4*)xp)[0];
  const float4 x1 = ((const float4*)xp)[1];
  float x[8] = {x0.x, x0.y, x0.z, x0.w, x1.x, x1.y, x1.z, x1.w};

  const float* wp = weight + (size_t)r * 1024 + b * 64 + op;
  float a0 = 0.f, a1 = 0.f;
  #pragma unroll
  for (int i = 0; i < 8; ++i) {
    const float2 w = *(const float2*)(wp + i * 8);
    a0 += x[i] * w.x;
    a1 += x[i] * w.y;
  }

  const int o = b * 8 + op;
  float* outp = out + (size_t)d * OUT_FEAT + o;
  atomicAdd(outp, a0 * nrm);
  atomicAdd(outp + 1, a1 * nrm);
}

__global__ __launch_bounds__(256) void relu_k(float* __restrict__ out, int n4) {
  const int i = blockIdx.x * blockDim.x + threadIdx.x;
  if (i < n4) {
    float4 v = ((const float4*)out)[i];
    v.x = fmaxf(v.x, 0.f);
    v.y = fmaxf(v.y, 0.f);
    v.z = fmaxf(v.z, 0.f);
    v.w = fmaxf(v.w, 0.f);
    ((float4*)out)[i] = v;
  }
}

extern "C" void kernel_launch(void* const* d_in, const int* in_sizes, int n_in,
                              void* d_out, int out_size, void* d_ws, size_t ws_size,
                              hipStream_t stream) {
  const float* h    = (const float*)d_in[0];
  const float* norm = (const float*)d_in[1];
  const float* w    = (const float*)d_in[2];
  const float* lw   = (const float*)d_in[3];
  const int* src    = (const int*)d_in[4];
  const int* dst    = (const int*)d_in[5];
  const int* etype  = (const int*)d_in[6];
  float* out = (float*)d_out;

  const int N = in_sizes[1];            // norm has N elements
  const int E = in_sizes[4];            // src has E elements
  const int R = in_sizes[2] / 1024;     // weight rows
  const int nblk = (N + SCAN_CHUNK - 1) / SCAN_CHUNK;

  // ws layout: srcet[E] int2 | cnt[N] | pos[N] | bsum[max(nblk,128)] |
  //            h16[N*128] bf16 | w16[R*1024] bf16 | lwT[128*128] bf16
  const size_t nb_bsum = (size_t)((nblk < 128) ? 128 : nblk);
  const size_t off_cnt  = (size_t)E * 8;
  const size_t off_pos  = off_cnt + (size_t)N * 4;
  const size_t off_bsum = off_pos + (size_t)N * 4;
  size_t off_h16 = off_bsum + nb_bsum * 4;
  off_h16 = (off_h16 + 15) & ~(size_t)15;
  const size_t off_w16 = off_h16 + (size_t)N * IN_FEAT * 2;
  const size_t off_lwT = off_w16 + (size_t)R * 1024 * 2;
  const size_t need_full = off_lwT + (size_t)IN_FEAT * OUT_FEAT * 2;
  const size_t need_sort = off_bsum + nb_bsum * 4;

  if (ws_size >= need_full) {
    char* wsb = (char*)d_ws;
    int2* srcet = (int2*)wsb;
    int* cnt  = (int*)(wsb + off_cnt);
    int* pos  = (int*)(wsb + off_pos);
    int* bsum = (int*)(wsb + off_bsum);
    unsigned short* h16 = (unsigned short*)(wsb + off_h16);
    unsigned short* w16 = (unsigned short*)(wsb + off_w16);
    unsigned short* lwT = (unsigned short*)(wsb + off_lwT);

    // --- try single cooperative pipeline dispatch ---
    int dev = 0;
    hipGetDevice(&dev);
    int coop = 0;
    hipDeviceGetAttribute(&coop, hipDeviceAttributeCooperativeLaunch, dev);
    int ncu = 0, maxb = 0;
    if (coop) {
      hipDeviceGetAttribute(&ncu, hipDeviceAttributeMultiprocessorCount, dev);
      hipOccupancyMaxActiveBlocksPerMultiprocessor(&maxb, k_pipeline, 256, 0);
    }
    const int grid = ncu * maxb;

    if (coop && grid > 0) {
      uint4* h16p = (uint4*)h16;
      void* args[] = {(void*)&w,   (void*)&h,    (void*)&lw,  (void*)&src,
                      (void*)&dst, (void*)&etype,(void*)&w16, (void*)&h16p,
                      (void*)&lwT, (void*)&cnt,  (void*)&pos, (void*)&srcet,
                      (void*)&out, (void*)&N,    (void*)&E,   (void*)&R};
      hipLaunchCooperativeKernel((void*)k_pipeline, dim3(grid), dim3(256),
                                 args, 0, stream);
      agg_bf16<<<(N + 3) / 4, 256, 0, stream>>>(h16, norm, w16, pos, cnt,
                                                srcet, out, N);
    } else {
      // round-7 multi-dispatch path
      hipMemsetAsync(cnt, 0, (size_t)N * 4, stream);
      const int htotal8 = N * IN_FEAT / 8;
      const int bw  = R;
      const int bh  = (htotal8 + 255) / 256;
      const int blw = (IN_FEAT * OUT_FEAT + 255) / 256;
      const int bhist = (E + 1023) / 1024;
      k_prep<<<bw + bh + blw + bhist, 256, 0, stream>>>(
          w, w16, h, (uint4*)h16, htotal8, lw, lwT, dst, cnt, E, bw, bh, blw);
      const int gemm_blocks = (N + 63) / 64;
      k_gemm_sum<<<gemm_blocks + nblk, 256, 0, stream>>>(
          h16, lwT, out, N, cnt, bsum, gemm_blocks);
      k_offsets<<<nblk, 256, 0, stream>>>(cnt, bsum, pos, N);
      k_scatter<<<(E + 1023) / 1024, 256, 0, stream>>>(src, dst, etype, pos,
                                                       srcet, E);
      agg_bf16<<<(N + 3) / 4, 256, 0, stream>>>(h16, norm, w16, pos, cnt,
                                                srcet, out, N);
    }
  } else if (ws_size >= need_sort) {
    char* wsb = (char*)d_ws;
    int2* srcet = (int2*)wsb;
    int* cnt  = (int*)(wsb + off_cnt);
    int* pos  = (int*)(wsb + off_pos);
    int* bsum = (int*)(wsb + off_bsum);

    selfloop_gemm<<<512, 256, 0, stream>>>(h, lw, out, N);
    hipMemsetAsync(cnt, 0, (size_t)N * 4, stream);
    k_hist<<<(E + 255) / 256, 256, 0, stream>>>(dst, cnt, E);
    k_chunksum<<<nblk, 256, 0, stream>>>(cnt, bsum, N);
    k_offsets<<<nblk, 256, 0, stream>>>(cnt, bsum, pos, N);
    k_scatter<<<(E + 1023) / 1024, 256, 0, stream>>>(src, dst, etype, pos,
                                                     srcet, E);
    agg<<<(N + 3) / 4, 256, 0, stream>>>(h, norm, w, pos, cnt, srcet, out, N);
  } else {
    selfloop_gemm<<<512, 256, 0, stream>>>(h, lw, out, N);
    edge_msg<<<(E + 3) / 4, 256, 0, stream>>>(h, norm, w, src, dst, etype, out, E);
    const int n4 = N * OUT_FEAT / 4;
    relu_k<<<(n4 + 255) / 256, 256, 0, stream>>>(out, n4);
  }
}

// Round 10
// 169.862 us; speedup vs baseline: 1.9347x; 1.9347x over previous
//
#include <hip/hip_runtime.h>
#include <hip/hip_bf16.h>

// RGCN layer: out = relu( segment_sum(blockdiag_msg) * norm + h @ loop_weight )
//
// Inputs (setup_inputs order):
//   0: h           [N,128]  f32
//   1: norm        [N,1]    f32
//   2: weight      [R,1024] f32   (R x NB(16) x SI(8) x SO(8))
//   3: loop_weight [128,128] f32
//   4: src         [E] i32
//   5: dst         [E] i32
//   6: etype       [E] i32
// Output: [N,128] f32
//
// Round-9: r8's cooperative grid.sync cost ~80-100us/sync on 8-XCD MI355X
// (400us total) -> reverted. Instead: fuse the self-loop MFMA GEMM INTO the
// aggregation kernel (16-node tile -> 8KB LDS, epilogue reads prev from LDS)
// eliminating the 25.6MB out write + 25.6MB re-read and one dispatch; each
// wave aggregates 4 nodes. k_offsets self-computes its chunk prefix from cnt
// (chunksum/bsum dropped). Chain: memset, k_prep, k_offsets, k_scatter,
// agg_fused = 5 dispatches (was 6). agg inner loop = r7 proven form.

#define IN_FEAT 128
#define OUT_FEAT 128
#define SCAN_CHUNK 512

using short8  = __attribute__((ext_vector_type(8))) short;
using float4v = __attribute__((ext_vector_type(4))) float;

__device__ inline float blo(unsigned u) { return __uint_as_float(u << 16); }
__device__ inline float bhi(unsigned u) { return __uint_as_float(u & 0xffff0000u); }
__device__ inline unsigned short f2bf(float f) {
  __hip_bfloat16 b = __float2bfloat16(f);
  return *reinterpret_cast<unsigned short*>(&b);
}

// dword = 2 packed bf16; returns c + x.lo*w.lo + x.hi*w.hi
__device__ inline float dot2bf(unsigned x, unsigned w, float c) {
#if __has_builtin(__builtin_amdgcn_fdot2_f32_bf16)
  typedef __bf16 bf16x2 __attribute__((ext_vector_type(2)));
  return __builtin_amdgcn_fdot2_f32_bf16(__builtin_bit_cast(bf16x2, x),
                                         __builtin_bit_cast(bf16x2, w), c, false);
#else
  return c + blo(x) * blo(w) + bhi(x) * bhi(w);
#endif
}

// ---------------------------------------------------------------------------
// Fused prologue: [wpack | hpack | lwpack | hist(x4)] by blockIdx range.
// wpack: one block per relation r. Stage w row (4KB f32) in LDS coalesced,
//   write w16[r][b*64+opp*16+j*8+i] = bf16(w[r][b*64+i*8+opp*2+j]) coalesced.
// hpack: h16 row-major bf16 copy of h (uint4 in/out).
// lwpack: lwT[o*128 + k] = bf16(lw[k*128 + o])  (col-major for MFMA B-frags).
// hist: cnt[dst[e]]++ with int4 loads, 4 edges/thread (cnt pre-zeroed).
// ---------------------------------------------------------------------------
__global__ __launch_bounds__(256) void k_prep(
    const float* __restrict__ w, unsigned short* __restrict__ w16,
    const float* __restrict__ h, uint4* __restrict__ h16p, int htotal8,
    const float* __restrict__ lw, unsigned short* __restrict__ lwT,
    const int* __restrict__ dst, int* __restrict__ cnt, int E,
    int bw, int bh, int blw) {
  __shared__ float srow[1024];
  const int bid = blockIdx.x;
  if (bid < bw) {  // bw == R; one relation per block
    const float* wr = w + ((size_t)bid << 10);
    ((float4*)srow)[threadIdx.x] = ((const float4*)wr)[threadIdx.x];
    __syncthreads();
    const int d0 = threadIdx.x * 4;
    unsigned short o4[4];
    #pragma unroll
    for (int k = 0; k < 4; ++k) {
      const int d = d0 + k;
      const int b = d >> 6;
      const int q = d & 63;
      const int opp = q >> 4;
      const int tt = q & 15;
      const int jj = tt >> 3;
      const int ii = tt & 7;
      o4[k] = f2bf(srow[b * 64 + ii * 8 + opp * 2 + jj]);
    }
    *(uint2*)(w16 + ((size_t)bid << 10) + d0) =
        make_uint2((unsigned)o4[0] | ((unsigned)o4[1] << 16),
                   (unsigned)o4[2] | ((unsigned)o4[3] << 16));
  } else if (bid < bw + bh) {
    const int t = (bid - bw) * 256 + threadIdx.x;
    if (t < htotal8) {
      const float4 a = ((const float4*)h)[2 * t];
      const float4 b = ((const float4*)h)[2 * t + 1];
      uint4 o;
      o.x = (unsigned)f2bf(a.x) | ((unsigned)f2bf(a.y) << 16);
      o.y = (unsigned)f2bf(a.z) | ((unsigned)f2bf(a.w) << 16);
      o.z = (unsigned)f2bf(b.x) | ((unsigned)f2bf(b.y) << 16);
      o.w = (unsigned)f2bf(b.z) | ((unsigned)f2bf(b.w) << 16);
      h16p[t] = o;
    }
  } else if (bid < bw + bh + blw) {
    const int idx = (bid - bw - bh) * 256 + threadIdx.x;
    if (idx < IN_FEAT * OUT_FEAT) {
      const int o = idx >> 7;
      const int k = idx & 127;
      lwT[idx] = f2bf(lw[k * 128 + o]);
    }
  } else {
    const int e0 = ((bid - bw - bh - blw) * 256 + threadIdx.x) * 4;
    if (e0 + 3 < E) {
      const int4 d4 = *(const int4*)(dst + e0);
      atomicAdd(&cnt[d4.x], 1);
      atomicAdd(&cnt[d4.y], 1);
      atomicAdd(&cnt[d4.z], 1);
      atomicAdd(&cnt[d4.w], 1);
    } else {
      for (int e = e0; e < E; ++e) atomicAdd(&cnt[dst[e]], 1);
    }
  }
}

// ---------------------------------------------------------------------------
// Per-chunk exclusive scan writing pos; block vb computes its own chunk
// prefix by summing cnt[0 .. vb*512) directly (no bsum kernel needed).
// ---------------------------------------------------------------------------
__global__ __launch_bounds__(256) void k_offsets_sp(
    const int* __restrict__ cnt, int* __restrict__ pos, int N) {
  __shared__ int s[256];
  __shared__ int sbase;
  const int t = threadIdx.x;
  const int vb = blockIdx.x;
  // chunk prefix = sum cnt[0 .. vb*512)
  {
    const int lim = vb * SCAN_CHUNK;
    int acc = 0;
    for (int i = t; i < lim; i += 256) acc += cnt[i];
    s[t] = acc;
    __syncthreads();
    for (int d = 128; d > 0; d >>= 1) {
      if (t < d) s[t] += s[t + d];
      __syncthreads();
    }
    if (t == 0) sbase = s[0];
    __syncthreads();
  }
  // exclusive scan of this chunk
  const int base = vb * SCAN_CHUNK;
  const int i0 = base + 2 * t;
  const int i1 = i0 + 1;
  const int c0 = (i0 < N) ? cnt[i0] : 0;
  const int c1 = (i1 < N) ? cnt[i1] : 0;
  const int pair = c0 + c1;
  s[t] = pair;
  __syncthreads();
  #pragma unroll
  for (int d = 1; d < 256; d <<= 1) {
    int v = (t >= d) ? s[t - d] : 0;
    __syncthreads();
    s[t] += v;
    __syncthreads();
  }
  const int ex = s[t] - pair + sbase;  // exclusive prefix
  if (i0 < N) pos[i0] = ex;
  if (i1 < N) pos[i1] = ex + c0;
}

// 4 edges/thread, int4 loads.
__global__ __launch_bounds__(256) void k_scatter(
    const int* __restrict__ src, const int* __restrict__ dst,
    const int* __restrict__ etype, int* __restrict__ pos,
    int2* __restrict__ srcet, int E) {
  const int e0 = (blockIdx.x * blockDim.x + threadIdx.x) * 4;
  if (e0 + 3 < E) {
    const int4 s4 = *(const int4*)(src + e0);
    const int4 d4 = *(const int4*)(dst + e0);
    const int4 t4 = *(const int4*)(etype + e0);
    int p;
    p = atomicAdd(&pos[d4.x], 1); srcet[p] = make_int2(s4.x, t4.x);
    p = atomicAdd(&pos[d4.y], 1); srcet[p] = make_int2(s4.y, t4.y);
    p = atomicAdd(&pos[d4.z], 1); srcet[p] = make_int2(s4.z, t4.z);
    p = atomicAdd(&pos[d4.w], 1); srcet[p] = make_int2(s4.w, t4.w);
  } else {
    for (int e = e0; e < E; ++e) {
      const int p = atomicAdd(&pos[dst[e]], 1);
      srcet[p] = make_int2(src[e], etype[e]);
    }
  }
}

// ---------------------------------------------------------------------------
// Fused GEMM + aggregation. Block = 4 waves = 16 nodes.
// Phase 1 (MFMA): block computes loop_message for its 16 node-rows into
//   8KB LDS. Wave wid owns col-tiles nt = 2*wid, 2*wid+1 (16x16x32 bf16,
//   4 K-chunks each). C layout (m89-verified): row=(lane>>4)*4+r, col=lane&15.
// Phase 2 (edges): wave wid aggregates nodes node_base+wid*4+{0..3} with the
//   r7 proven inner loop (grouped h loads: one 16B load serves 4 edges' rows;
//   per edge 2x16B weight loads + 8 dot2). Epilogue reads prev from LDS:
//   out = relu(lmsg + acc*norm). No out round-trip through HBM.
// ---------------------------------------------------------------------------
__global__ __launch_bounds__(256) void agg_fused(
    const unsigned short* __restrict__ h16, const float* __restrict__ norm,
    const unsigned short* __restrict__ w16, const unsigned short* __restrict__ lwT,
    const int* __restrict__ pos, const int* __restrict__ cnt,
    const int2* __restrict__ srcet, float* __restrict__ out, int N) {
  __shared__ float lmsg[16][128];
  const int wid = threadIdx.x >> 6;
  const int lane = threadIdx.x & 63;
  const int node_base = blockIdx.x * 16;

  // ---- Phase 1: self-loop GEMM for 16 rows -> LDS ----
  {
    const int m = lane & 15;
    const int kg = (lane >> 4) * 8;
    const int arow = min(node_base + m, N - 1);
    const unsigned short* ap = h16 + (size_t)arow * 128 + kg;
    const unsigned short* bp = lwT + (size_t)m * 128 + kg;
    const int nt0 = wid * 2, nt1 = wid * 2 + 1;

    float4v acc0 = (float4v){0.f, 0.f, 0.f, 0.f};
    float4v acc1 = (float4v){0.f, 0.f, 0.f, 0.f};
    #pragma unroll
    for (int kc = 0; kc < 4; ++kc) {
      const short8 a  = *(const short8*)(ap + kc * 32);
      const short8 b0 = *(const short8*)(bp + nt0 * 2048 + kc * 32);
      const short8 b1 = *(const short8*)(bp + nt1 * 2048 + kc * 32);
      acc0 = __builtin_amdgcn_mfma_f32_16x16x32_bf16(a, b0, acc0, 0, 0, 0);
      acc1 = __builtin_amdgcn_mfma_f32_16x16x32_bf16(a, b1, acc1, 0, 0, 0);
    }
    const int rrow = (lane >> 4) * 4;
    #pragma unroll
    for (int r = 0; r < 4; ++r) {
      lmsg[rrow + r][nt0 * 16 + m] = acc0[r];
      lmsg[rrow + r][nt1 * 16 + m] = acc1[r];
    }
  }
  __syncthreads();

  // ---- Phase 2: edge aggregation, 4 nodes per wave ----
  const int b = lane >> 2;
  const int opp = lane & 3;
  const int woff = b * 64 + opp * 16;  // ushort units
  const int o = b * 8 + opp * 2;

  for (int u = 0; u < 4; ++u) {
    const int node = node_base + wid * 4 + u;
    if (node >= N) continue;  // no barriers below; whole-wave uniform

    const int num = cnt[node];
    const int end = pos[node];
    const int begin = end - num;

    float a0 = 0.f, a1 = 0.f;

    for (int base = 0; base < num; base += 64) {
      const int cn = min(64, num - base);
      const int2 my = srcet[begin + base + min(lane, cn - 1)];
      for (int i4 = 0; i4 < cn; i4 += 4) {
        const int gl = min(i4 + (lane >> 4), cn - 1);
        const int sg = __shfl(my.x, gl);
        const uint4 xq =
            *(const uint4*)(h16 + ((size_t)sg << 7) + (lane & 15) * 8);
        const int nin = min(4, cn - i4);
        #pragma unroll 4
        for (int v = 0; v < nin; ++v) {
          const int r = __shfl(my.y, i4 + v);
          const int sl = v * 16 + b;
          uint4 xv;
          xv.x = __shfl(xq.x, sl);
          xv.y = __shfl(xq.y, sl);
          xv.z = __shfl(xq.z, sl);
          xv.w = __shfl(xq.w, sl);
          const unsigned short* wp = w16 + ((size_t)r << 10) + woff;
          const uint4 wa = *(const uint4*)(wp);
          const uint4 wb = *(const uint4*)(wp + 8);

          a0 = dot2bf(xv.x, wa.x, a0);
          a0 = dot2bf(xv.y, wa.y, a0);
          a0 = dot2bf(xv.z, wa.z, a0);
          a0 = dot2bf(xv.w, wa.w, a0);
          a1 = dot2bf(xv.x, wb.x, a1);
          a1 = dot2bf(xv.y, wb.y, a1);
          a1 = dot2bf(xv.z, wb.z, a1);
          a1 = dot2bf(xv.w, wb.w, a1);
        }
      }
    }

    const float nm = norm[node];
    const float2 prev = *(const float2*)&lmsg[wid * 4 + u][o];
    float2 res;
    res.x = fmaxf(prev.x + a0 * nm, 0.f);
    res.y = fmaxf(prev.y + a1 * nm, 0.f);
    *(float2*)(out + ((size_t)node << 7) + o) = res;
  }
}

// ===========================================================================
// Fallback kernels (middle / minimal ws paths)
// ===========================================================================
__global__ __launch_bounds__(256) void k_hist(
    const int* __restrict__ dst, int* __restrict__ cnt, int E) {
  const int e = blockIdx.x * blockDim.x + threadIdx.x;
  if (e < E) atomicAdd(&cnt[dst[e]], 1);
}

__global__ __launch_bounds__(256) void selfloop_gemm(
    const float* __restrict__ h, const float* __restrict__ lw,
    float* __restrict__ out, int n) {
  __shared__ float slw[IN_FEAT * OUT_FEAT];
  __shared__ float sh[32 * IN_FEAT];

  {
    const float4* s4 = (const float4*)lw;
    float4* d4 = (float4*)slw;
    for (int i = threadIdx.x; i < IN_FEAT * OUT_FEAT / 4; i += 256) d4[i] = s4[i];
  }

  const int cg_ = threadIdx.x & 31;
  const int rg = threadIdx.x >> 5;

  for (int base = blockIdx.x * 32; base < n; base += gridDim.x * 32) {
    const int nrows = min(32, n - base);
    __syncthreads();
    {
      const float4* hs = (const float4*)(h + (size_t)base * IN_FEAT);
      float4* sd = (float4*)sh;
      const int cnt = nrows * (IN_FEAT / 4);
      for (int i = threadIdx.x; i < cnt; i += 256) sd[i] = hs[i];
    }
    __syncthreads();

    float4 acc[4];
    #pragma unroll
    for (int j = 0; j < 4; ++j) acc[j] = make_float4(0.f, 0.f, 0.f, 0.f);

    #pragma unroll 4
    for (int k = 0; k < IN_FEAT; ++k) {
      const float4 w = ((const float4*)slw)[k * 32 + cg_];
      #pragma unroll
      for (int j = 0; j < 4; ++j) {
        const float hv = sh[(rg + 8 * j) * IN_FEAT + k];
        acc[j].x += hv * w.x;
        acc[j].y += hv * w.y;
        acc[j].z += hv * w.z;
        acc[j].w += hv * w.w;
      }
    }

    #pragma unroll
    for (int j = 0; j < 4; ++j) {
      const int r = rg + 8 * j;
      if (r < nrows) {
        ((float4*)(out + (size_t)(base + r) * OUT_FEAT))[cg_] = acc[j];
      }
    }
  }
}

__global__ __launch_bounds__(256) void agg(
    const float* __restrict__ h, const float* __restrict__ norm,
    const float* __restrict__ weight, const int* __restrict__ pos,
    const int* __restrict__ cnt, const int2* __restrict__ srcet,
    float* __restrict__ out, int N) {
  const int node = (int)((blockIdx.x * blockDim.x + threadIdx.x) >> 6);
  const int lane = threadIdx.x & 63;
  if (node >= N) return;

  const int b = lane >> 2;
  const int op = (lane & 3) * 2;
  const int boff = b * 64 + op;

  const int num = cnt[node];
  const int end = pos[node];
  const int begin = end - num;

  float a0 = 0.f, a1 = 0.f;

  for (int base = 0; base < num; base += 64) {
    const int cn = min(64, num - base);
    const int2 my = srcet[begin + base + min(lane, cn - 1)];
    #pragma unroll 2
    for (int i = 0; i < cn; ++i) {
      const int s = __shfl(my.x, i);
      const int r = __shfl(my.y, i);
      const float* xp = h + ((size_t)s << 7) + b * 8;
      const float4 x0 = ((const float4*)xp)[0];
      const float4 x1 = ((const float4*)xp)[1];
      const float* wp = weight + ((size_t)r << 10) + boff;
      const float2 w0 = *(const float2*)(wp);
      const float2 w1 = *(const float2*)(wp + 8);
      const float2 w2 = *(const float2*)(wp + 16);
      const float2 w3 = *(const float2*)(wp + 24);
      const float2 w4 = *(const float2*)(wp + 32);
      const float2 w5 = *(const float2*)(wp + 40);
      const float2 w6 = *(const float2*)(wp + 48);
      const float2 w7 = *(const float2*)(wp + 56);
      a0 += x0.x * w0.x; a1 += x0.x * w0.y;
      a0 += x0.y * w1.x; a1 += x0.y * w1.y;
      a0 += x0.z * w2.x; a1 += x0.z * w2.y;
      a0 += x0.w * w3.x; a1 += x0.w * w3.y;
      a0 += x1.x * w4.x; a1 += x1.x * w4.y;
      a0 += x1.y * w5.x; a1 += x1.y * w5.y;
      a0 += x1.z * w6.x; a1 += x1.z * w6.y;
      a0 += x1.w * w7.x; a1 += x1.w * w7.y;
    }
  }

  const float nm = norm[node];
  const int o = b * 8 + op;
  float* outp = out + ((size_t)node << 7) + o;
  float2 prev = *(const float2*)outp;
  float2 res;
  res.x = fmaxf(prev.x + a0 * nm, 0.f);
  res.y = fmaxf(prev.y + a1 * nm, 0.f);
  *(float2*)outp = res;
}

__global__ __launch_bounds__(256) void edge_msg(
    const float* __restrict__ h, const float* __restrict__ norm,
    const float* __restrict__ weight, const int* __restrict__ src,
    const int* __restrict__ dst, const int* __restrict__ etype,
    float* out, int E) {
  const int wave = (int)((blockIdx.x * blockDim.x + threadIdx.x) >> 6);
  const int lane = threadIdx.x & 63;
  if (wave >= E) return;

  const int s = src[wave];
  const int d = dst[wave];
  const int r = etype[wave];
  const float nrm = norm[d];

  const int b = lane >> 2;
  const int op = (lane & 3) * 2;

  const float* xp = h + (size_t)s * IN_FEAT + b * 8;
  const float4 x0 = ((const float4*)xp)[0];
  const float4 x1 = ((const float4*)xp)[1];
  float x[8] = {x0.x, x0.y, x0.z, x0.w, x1.x, x1.y, x1.z, x1.w};

  const float* wp = weight + (size_t)r * 1024 + b * 64 + op;
  float a0 = 0.f, a1 = 0.f;
  #pragma unroll
  for (int i = 0; i < 8; ++i) {
    const float2 w = *(const float2*)(wp + i * 8);
    a0 += x[i] * w.x;
    a1 += x[i] * w.y;
  }

  const int o = b * 8 + op;
  float* outp = out + (size_t)d * OUT_FEAT + o;
  atomicAdd(outp, a0 * nrm);
  atomicAdd(outp + 1, a1 * nrm);
}

__global__ __launch_bounds__(256) void relu_k(float* __restrict__ out, int n4) {
  const int i = blockIdx.x * blockDim.x + threadIdx.x;
  if (i < n4) {
    float4 v = ((const float4*)out)[i];
    v.x = fmaxf(v.x, 0.f);
    v.y = fmaxf(v.y, 0.f);
    v.z = fmaxf(v.z, 0.f);
    v.w = fmaxf(v.w, 0.f);
    ((float4*)out)[i] = v;
  }
}

extern "C" void kernel_launch(void* const* d_in, const int* in_sizes, int n_in,
                              void* d_out, int out_size, void* d_ws, size_t ws_size,
                              hipStream_t stream) {
  const float* h    = (const float*)d_in[0];
  const float* norm = (const float*)d_in[1];
  const float* w    = (const float*)d_in[2];
  const float* lw   = (const float*)d_in[3];
  const int* src    = (const int*)d_in[4];
  const int* dst    = (const int*)d_in[5];
  const int* etype  = (const int*)d_in[6];
  float* out = (float*)d_out;

  const int N = in_sizes[1];            // norm has N elements
  const int E = in_sizes[4];            // src has E elements
  const int R = in_sizes[2] / 1024;     // weight rows
  const int nblk = (N + SCAN_CHUNK - 1) / SCAN_CHUNK;

  // ws layout: srcet[E] int2 | cnt[N] | pos[N] | bsum[128] (legacy) |
  //            h16[N*128] bf16 | w16[R*1024] bf16 | lwT[128*128] bf16
  const size_t nb_bsum = (size_t)((nblk < 128) ? 128 : nblk);
  const size_t off_cnt  = (size_t)E * 8;
  const size_t off_pos  = off_cnt + (size_t)N * 4;
  const size_t off_bsum = off_pos + (size_t)N * 4;
  size_t off_h16 = off_bsum + nb_bsum * 4;
  off_h16 = (off_h16 + 15) & ~(size_t)15;
  const size_t off_w16 = off_h16 + (size_t)N * IN_FEAT * 2;
  const size_t off_lwT = off_w16 + (size_t)R * 1024 * 2;
  const size_t need_full = off_lwT + (size_t)IN_FEAT * OUT_FEAT * 2;
  const size_t need_sort = off_bsum + nb_bsum * 4;

  if (ws_size >= need_full) {
    char* wsb = (char*)d_ws;
    int2* srcet = (int2*)wsb;
    int* cnt  = (int*)(wsb + off_cnt);
    int* pos  = (int*)(wsb + off_pos);
    unsigned short* h16 = (unsigned short*)(wsb + off_h16);
    unsigned short* w16 = (unsigned short*)(wsb + off_w16);
    unsigned short* lwT = (unsigned short*)(wsb + off_lwT);

    hipMemsetAsync(cnt, 0, (size_t)N * 4, stream);

    // fused prologue: wpack (1 block/relation) + hpack + lwpack + hist (x4)
    const int htotal8 = N * IN_FEAT / 8;
    const int bw  = R;
    const int bh  = (htotal8 + 255) / 256;
    const int blw = (IN_FEAT * OUT_FEAT + 255) / 256;
    const int bhist = (E + 1023) / 1024;
    k_prep<<<bw + bh + blw + bhist, 256, 0, stream>>>(
        w, w16, h, (uint4*)h16, htotal8, lw, lwT, dst, cnt, E, bw, bh, blw);

    // offsets (self-computed chunk prefix) + scatter (4 edges/thread)
    k_offsets_sp<<<nblk, 256, 0, stream>>>(cnt, pos, N);
    k_scatter<<<(E + 1023) / 1024, 256, 0, stream>>>(src, dst, etype, pos,
                                                     srcet, E);

    // fused MFMA self-loop GEMM (LDS) + aggregation + epilogue
    agg_fused<<<(N + 15) / 16, 256, 0, stream>>>(h16, norm, w16, lwT, pos, cnt,
                                                 srcet, out, N);
  } else if (ws_size >= need_sort) {
    char* wsb = (char*)d_ws;
    int2* srcet = (int2*)wsb;
    int* cnt  = (int*)(wsb + off_cnt);
    int* pos  = (int*)(wsb + off_pos);

    selfloop_gemm<<<512, 256, 0, stream>>>(h, lw, out, N);
    hipMemsetAsync(cnt, 0, (size_t)N * 4, stream);
    k_hist<<<(E + 255) / 256, 256, 0, stream>>>(dst, cnt, E);
    k_offsets_sp<<<nblk, 256, 0, stream>>>(cnt, pos, N);
    k_scatter<<<(E + 1023) / 1024, 256, 0, stream>>>(src, dst, etype, pos,
                                                     srcet, E);
    agg<<<(N + 3) / 4, 256, 0, stream>>>(h, norm, w, pos, cnt, srcet, out, N);
  } else {
    selfloop_gemm<<<512, 256, 0, stream>>>(h, lw, out, N);
    edge_msg<<<(E + 3) / 4, 256, 0, stream>>>(h, norm, w, src, dst, etype, out, E);
    const int n4 = N * OUT_FEAT / 4;
    relu_k<<<(n4 + 255) / 256, 256, 0, stream>>>(out, n4);
  }
}

// Round 11
// 163.821 us; speedup vs baseline: 2.0061x; 1.0369x over previous
//
#include <hip/hip_runtime.h>
#include <hip/hip_bf16.h>

// RGCN layer: out = relu( segment_sum(blockdiag_msg) * norm + h @ loop_weight )
//
// Inputs (setup_inputs order):
//   0: h           [N,128]  f32
//   1: norm        [N,1]    f32
//   2: weight      [R,1024] f32   (R x NB(16) x SI(8) x SO(8))
//   3: loop_weight [128,128] f32
//   4: src         [E] i32
//   5: dst         [E] i32
//   6: etype       [E] i32
// Output: [N,128] f32
//
// Round-10: r9 fusion of gemm INTO agg cut wave count 4x and regressed
// (agg needs max TLP for the L2 gather). Keep agg = r7 one-wave-per-node
// (58us proven). Instead fold the MFMA self-loop GEMM into k_prep as an
// independent block range: each gemm block stages its own 32-col slice of
// loop_weight f32 -> bf16 transposed LDS (8.7KB, +8 pad) and reads A-frags
// from f32 h directly -> no lwT dependency, lwpack dropped. Chain:
// memset, k_prep(wpack|hpack|gemm|hist), k_offsets_sp, k_scatter, agg_bf16
// = 5 dispatches (r7 had 6).

#define IN_FEAT 128
#define OUT_FEAT 128
#define SCAN_CHUNK 512

using short8  = __attribute__((ext_vector_type(8))) short;
using float4v = __attribute__((ext_vector_type(4))) float;

__device__ inline float blo(unsigned u) { return __uint_as_float(u << 16); }
__device__ inline float bhi(unsigned u) { return __uint_as_float(u & 0xffff0000u); }
__device__ inline unsigned short f2bf(float f) {
  __hip_bfloat16 b = __float2bfloat16(f);
  return *reinterpret_cast<unsigned short*>(&b);
}

// dword = 2 packed bf16; returns c + x.lo*w.lo + x.hi*w.hi
__device__ inline float dot2bf(unsigned x, unsigned w, float c) {
#if __has_builtin(__builtin_amdgcn_fdot2_f32_bf16)
  typedef __bf16 bf16x2 __attribute__((ext_vector_type(2)));
  return __builtin_amdgcn_fdot2_f32_bf16(__builtin_bit_cast(bf16x2, x),
                                         __builtin_bit_cast(bf16x2, w), c, false);
#else
  return c + blo(x) * blo(w) + bhi(x) * bhi(w);
#endif
}

__device__ inline short8 pack8(const float4 a, const float4 b) {
  short8 r;
  r[0] = (short)f2bf(a.x); r[1] = (short)f2bf(a.y);
  r[2] = (short)f2bf(a.z); r[3] = (short)f2bf(a.w);
  r[4] = (short)f2bf(b.x); r[5] = (short)f2bf(b.y);
  r[6] = (short)f2bf(b.z); r[7] = (short)f2bf(b.w);
  return r;
}

// ---------------------------------------------------------------------------
// Fused prologue: [wpack | hpack | gemm | hist(x4)] by blockIdx range.
// wpack: one block per relation r; LDS-staged permuted bf16 pack (dot2 layout)
//   w16[r][b*64+opp*16+j*8+i] = bf16(w[r][b*64+i*8+opp*2+j]).
// hpack: h16 row-major bf16 copy of h (uint4 in/out).
// gemm: out = h @ loop_weight via MFMA. Block g: vb=g>>2 (64 rows),
//   cp=g&3 (32-col slice). Stage lw[:, cp*32..+31] f32 -> bf16 transposed
//   LDS [32][136] (pad 8 kills store conflicts); A-frags converted in-reg
//   from f32 h. No dependency on any other range.
// hist: cnt[dst[e]]++ with int4 loads, 4 edges/thread (cnt pre-zeroed).
// ---------------------------------------------------------------------------
__global__ __launch_bounds__(256) void k_prep(
    const float* __restrict__ w, unsigned short* __restrict__ w16,
    const float* __restrict__ h, uint4* __restrict__ h16p, int htotal8,
    const float* __restrict__ lw, const int* __restrict__ dst,
    int* __restrict__ cnt, int E, float* __restrict__ out, int N,
    int bw, int bh, int bg) {
  __shared__ char smem[32 * 136 * 2];  // 8704 B, aliased per range
  const int bid = blockIdx.x;
  const int tid = threadIdx.x;

  if (bid < bw) {  // ---- wpack: one relation per block ----
    float* srow = (float*)smem;  // 1024 floats staged in two halves
    const float* wr = w + ((size_t)bid << 10);
    // stage half 1 (512 floats), emit, then half 2 to fit 8.7KB LDS
    #pragma unroll
    for (int half = 0; half < 2; ++half) {
      ((float2*)srow)[tid] = ((const float2*)(wr + half * 512))[tid];
      __syncthreads();
      // each thread emits 2 outputs in [half*512, half*512+512)
      #pragma unroll
      for (int k = 0; k < 2; ++k) {
        const int d = half * 512 + tid * 2 + k;
        const int b = d >> 6;
        const int q = d & 63;
        const int opp = q >> 4;
        const int tt = q & 15;
        const int jj = tt >> 3;
        const int ii = tt & 7;
        const int srci = b * 64 + ii * 8 + opp * 2 + jj;
        // srci may fall in either half; both halves of w row are needed.
        // Stage covers only `half`; fall back to global read if out of range.
        float v;
        if (srci >= half * 512 && srci < half * 512 + 512)
          v = srow[srci - half * 512];
        else
          v = wr[srci];
        w16[((size_t)bid << 10) + d] = f2bf(v);
      }
      __syncthreads();
    }
  } else if (bid < bw + bh) {  // ---- hpack ----
    const int t = (bid - bw) * 256 + tid;
    if (t < htotal8) {
      const float4 a = ((const float4*)h)[2 * t];
      const float4 b = ((const float4*)h)[2 * t + 1];
      uint4 o;
      o.x = (unsigned)f2bf(a.x) | ((unsigned)f2bf(a.y) << 16);
      o.y = (unsigned)f2bf(a.z) | ((unsigned)f2bf(a.w) << 16);
      o.z = (unsigned)f2bf(b.x) | ((unsigned)f2bf(b.y) << 16);
      o.w = (unsigned)f2bf(b.z) | ((unsigned)f2bf(b.w) << 16);
      h16p[t] = o;
    }
  } else if (bid < bw + bh + bg) {  // ---- gemm ----
    unsigned short* slw = (unsigned short*)smem;  // [32][136]
    const int g = bid - bw - bh;
    const int vb = g >> 2;
    const int cp = g & 3;

    // stage lw[:, cp*32 .. cp*32+31] -> slw[c_local][k], bf16
    {
      const float4* lw4 = (const float4*)lw;  // [128][32] float4
      for (int i = tid; i < 1024; i += 256) {
        const int k = i >> 3;   // 0..127
        const int cq = i & 7;   // 0..7
        const float4 v = lw4[k * 32 + cp * 8 + cq];
        const int cl = cq * 4;
        slw[(cl + 0) * 136 + k] = f2bf(v.x);
        slw[(cl + 1) * 136 + k] = f2bf(v.y);
        slw[(cl + 2) * 136 + k] = f2bf(v.z);
        slw[(cl + 3) * 136 + k] = f2bf(v.w);
      }
    }
    __syncthreads();

    const int wid = tid >> 6;
    const int lane = tid & 63;
    const int m = lane & 15;
    const int kg = (lane >> 4) * 8;
    const int row0 = vb * 64 + wid * 16;
    if (row0 < N) {
      const int arow = min(row0 + m, N - 1);
      const float* hp = h + (size_t)arow * 128 + kg;
      const unsigned short* bp0 = slw + (0 * 16 + m) * 136 + kg;
      const unsigned short* bp1 = slw + (1 * 16 + m) * 136 + kg;

      float4v acc0 = (float4v){0.f, 0.f, 0.f, 0.f};
      float4v acc1 = (float4v){0.f, 0.f, 0.f, 0.f};
      #pragma unroll
      for (int kc = 0; kc < 4; ++kc) {
        const float4 a0 = *(const float4*)(hp + kc * 32);
        const float4 a1 = *(const float4*)(hp + kc * 32 + 4);
        const short8 a = pack8(a0, a1);
        const short8 b0 = *(const short8*)(bp0 + kc * 32);
        const short8 b1 = *(const short8*)(bp1 + kc * 32);
        acc0 = __builtin_amdgcn_mfma_f32_16x16x32_bf16(a, b0, acc0, 0, 0, 0);
        acc1 = __builtin_amdgcn_mfma_f32_16x16x32_bf16(a, b1, acc1, 0, 0, 0);
      }
      const int crow = row0 + (lane >> 4) * 4;
      const int col0 = cp * 32 + m;
      #pragma unroll
      for (int r = 0; r < 4; ++r) {
        const int row = crow + r;
        if (row < N) {
          out[(size_t)row * 128 + col0] = acc0[r];
          out[(size_t)row * 128 + col0 + 16] = acc1[r];
        }
      }
    }
  } else {  // ---- hist ----
    const int e0 = ((bid - bw - bh - bg) * 256 + tid) * 4;
    if (e0 + 3 < E) {
      const int4 d4 = *(const int4*)(dst + e0);
      atomicAdd(&cnt[d4.x], 1);
      atomicAdd(&cnt[d4.y], 1);
      atomicAdd(&cnt[d4.z], 1);
      atomicAdd(&cnt[d4.w], 1);
    } else {
      for (int e = e0; e < E; ++e) atomicAdd(&cnt[dst[e]], 1);
    }
  }
}

// ---------------------------------------------------------------------------
// Per-chunk exclusive scan writing pos; block vb computes its own chunk
// prefix by summing cnt[0 .. vb*512) directly (validated r9/r10).
// ---------------------------------------------------------------------------
__global__ __launch_bounds__(256) void k_offsets_sp(
    const int* __restrict__ cnt, int* __restrict__ pos, int N) {
  __shared__ int s[256];
  __shared__ int sbase;
  const int t = threadIdx.x;
  const int vb = blockIdx.x;
  {
    const int lim = vb * SCAN_CHUNK;
    int acc = 0;
    for (int i = t; i < lim; i += 256) acc += cnt[i];
    s[t] = acc;
    __syncthreads();
    for (int d = 128; d > 0; d >>= 1) {
      if (t < d) s[t] += s[t + d];
      __syncthreads();
    }
    if (t == 0) sbase = s[0];
    __syncthreads();
  }
  const int base = vb * SCAN_CHUNK;
  const int i0 = base + 2 * t;
  const int i1 = i0 + 1;
  const int c0 = (i0 < N) ? cnt[i0] : 0;
  const int c1 = (i1 < N) ? cnt[i1] : 0;
  const int pair = c0 + c1;
  s[t] = pair;
  __syncthreads();
  #pragma unroll
  for (int d = 1; d < 256; d <<= 1) {
    int v = (t >= d) ? s[t - d] : 0;
    __syncthreads();
    s[t] += v;
    __syncthreads();
  }
  const int ex = s[t] - pair + sbase;  // exclusive prefix
  if (i0 < N) pos[i0] = ex;
  if (i1 < N) pos[i1] = ex + c0;
}

// 4 edges/thread, int4 loads.
__global__ __launch_bounds__(256) void k_scatter(
    const int* __restrict__ src, const int* __restrict__ dst,
    const int* __restrict__ etype, int* __restrict__ pos,
    int2* __restrict__ srcet, int E) {
  const int e0 = (blockIdx.x * blockDim.x + threadIdx.x) * 4;
  if (e0 + 3 < E) {
    const int4 s4 = *(const int4*)(src + e0);
    const int4 d4 = *(const int4*)(dst + e0);
    const int4 t4 = *(const int4*)(etype + e0);
    int p;
    p = atomicAdd(&pos[d4.x], 1); srcet[p] = make_int2(s4.x, t4.x);
    p = atomicAdd(&pos[d4.y], 1); srcet[p] = make_int2(s4.y, t4.y);
    p = atomicAdd(&pos[d4.z], 1); srcet[p] = make_int2(s4.z, t4.z);
    p = atomicAdd(&pos[d4.w], 1); srcet[p] = make_int2(s4.w, t4.w);
  } else {
    for (int e = e0; e < E; ++e) {
      const int p = atomicAdd(&pos[dst[e]], 1);
      srcet[p] = make_int2(src[e], etype[e]);
    }
  }
}

// ---------------------------------------------------------------------------
// bf16 aggregation (r7 proven, 58us): one wave per node; lane (b,opp) owns
// outputs o=b*8+opp*2, o+1. Per 4-edge group one 16B load fetches all 4
// edges' h rows (lane=(edge,chunk)), distributed via shfl; per edge
// 2 x 16B weight loads + 8 dot2. Epilogue prev/norm prefetched.
// out = relu(out + acc*norm)   (out holds loop_message from k_prep gemm).
// ---------------------------------------------------------------------------
__global__ __launch_bounds__(256) void agg_bf16(
    const unsigned short* __restrict__ h16, const float* __restrict__ norm,
    const unsigned short* __restrict__ w16, const int* __restrict__ pos,
    const int* __restrict__ cnt, const int2* __restrict__ srcet,
    float* __restrict__ out, int N) {
  const int node = (int)((blockIdx.x * blockDim.x + threadIdx.x) >> 6);
  const int lane = threadIdx.x & 63;
  if (node >= N) return;

  const int b = lane >> 2;
  const int opp = lane & 3;
  const int woff = b * 64 + opp * 16;  // ushort units
  const int o = b * 8 + opp * 2;

  const int num = cnt[node];
  const int end = pos[node];
  const int begin = end - num;

  float* outp = out + ((size_t)node << 7) + o;
  const float2 prev = *(const float2*)outp;
  const float nm = norm[node];

  float a0 = 0.f, a1 = 0.f;

  for (int base = 0; base < num; base += 64) {
    const int cn = min(64, num - base);
    const int2 my = srcet[begin + base + min(lane, cn - 1)];
    for (int i4 = 0; i4 < cn; i4 += 4) {
      const int gl = min(i4 + (lane >> 4), cn - 1);
      const int sg = __shfl(my.x, gl);
      const uint4 xq =
          *(const uint4*)(h16 + ((size_t)sg << 7) + (lane & 15) * 8);
      const int nin = min(4, cn - i4);
      #pragma unroll 4
      for (int u = 0; u < nin; ++u) {
        const int r = __shfl(my.y, i4 + u);
        const int sl = u * 16 + b;
        uint4 xv;
        xv.x = __shfl(xq.x, sl);
        xv.y = __shfl(xq.y, sl);
        xv.z = __shfl(xq.z, sl);
        xv.w = __shfl(xq.w, sl);
        const unsigned short* wp = w16 + ((size_t)r << 10) + woff;
        const uint4 wa = *(const uint4*)(wp);
        const uint4 wb = *(const uint4*)(wp + 8);

        a0 = dot2bf(xv.x, wa.x, a0);
        a0 = dot2bf(xv.y, wa.y, a0);
        a0 = dot2bf(xv.z, wa.z, a0);
        a0 = dot2bf(xv.w, wa.w, a0);
        a1 = dot2bf(xv.x, wb.x, a1);
        a1 = dot2bf(xv.y, wb.y, a1);
        a1 = dot2bf(xv.z, wb.z, a1);
        a1 = dot2bf(xv.w, wb.w, a1);
      }
    }
  }

  float2 res;
  res.x = fmaxf(prev.x + a0 * nm, 0.f);
  res.y = fmaxf(prev.y + a1 * nm, 0.f);
  *(float2*)outp = res;
}

// ===========================================================================
// Fallback kernels (middle / minimal ws paths)
// ===========================================================================
__global__ __launch_bounds__(256) void k_hist(
    const int* __restrict__ dst, int* __restrict__ cnt, int E) {
  const int e = blockIdx.x * blockDim.x + threadIdx.x;
  if (e < E) atomicAdd(&cnt[dst[e]], 1);
}

__global__ __launch_bounds__(256) void selfloop_gemm(
    const float* __restrict__ h, const float* __restrict__ lw,
    float* __restrict__ out, int n) {
  __shared__ float slw[IN_FEAT * OUT_FEAT];
  __shared__ float sh[32 * IN_FEAT];

  {
    const float4* s4 = (const float4*)lw;
    float4* d4 = (float4*)slw;
    for (int i = threadIdx.x; i < IN_FEAT * OUT_FEAT / 4; i += 256) d4[i] = s4[i];
  }

  const int cg_ = threadIdx.x & 31;
  const int rg = threadIdx.x >> 5;

  for (int base = blockIdx.x * 32; base < n; base += gridDim.x * 32) {
    const int nrows = min(32, n - base);
    __syncthreads();
    {
      const float4* hs = (const float4*)(h + (size_t)base * IN_FEAT);
      float4* sd = (float4*)sh;
      const int cnt = nrows * (IN_FEAT / 4);
      for (int i = threadIdx.x; i < cnt; i += 256) sd[i] = hs[i];
    }
    __syncthreads();

    float4 acc[4];
    #pragma unroll
    for (int j = 0; j < 4; ++j) acc[j] = make_float4(0.f, 0.f, 0.f, 0.f);

    #pragma unroll 4
    for (int k = 0; k < IN_FEAT; ++k) {
      const float4 w = ((const float4*)slw)[k * 32 + cg_];
      #pragma unroll
      for (int j = 0; j < 4; ++j) {
        const float hv = sh[(rg + 8 * j) * IN_FEAT + k];
        acc[j].x += hv * w.x;
        acc[j].y += hv * w.y;
        acc[j].z += hv * w.z;
        acc[j].w += hv * w.w;
      }
    }

    #pragma unroll
    for (int j = 0; j < 4; ++j) {
      const int r = rg + 8 * j;
      if (r < nrows) {
        ((float4*)(out + (size_t)(base + r) * OUT_FEAT))[cg_] = acc[j];
      }
    }
  }
}

__global__ __launch_bounds__(256) void agg(
    const float* __restrict__ h, const float* __restrict__ norm,
    const float* __restrict__ weight, const int* __restrict__ pos,
    const int* __restrict__ cnt, const int2* __restrict__ srcet,
    float* __restrict__ out, int N) {
  const int node = (int)((blockIdx.x * blockDim.x + threadIdx.x) >> 6);
  const int lane = threadIdx.x & 63;
  if (node >= N) return;

  const int b = lane >> 2;
  const int op = (lane & 3) * 2;
  const int boff = b * 64 + op;

  const int num = cnt[node];
  const int end = pos[node];
  const int begin = end - num;

  float a0 = 0.f, a1 = 0.f;

  for (int base = 0; base < num; base += 64) {
    const int cn = min(64, num - base);
    const int2 my = srcet[begin + base + min(lane, cn - 1)];
    #pragma unroll 2
    for (int i = 0; i < cn; ++i) {
      const int s = __shfl(my.x, i);
      const int r = __shfl(my.y, i);
      const float* xp = h + ((size_t)s << 7) + b * 8;
      const float4 x0 = ((const float4*)xp)[0];
      const float4 x1 = ((const float4*)xp)[1];
      const float* wp = weight + ((size_t)r << 10) + boff;
      const float2 w0 = *(const float2*)(wp);
      const float2 w1 = *(const float2*)(wp + 8);
      const float2 w2 = *(const float2*)(wp + 16);
      const float2 w3 = *(const float2*)(wp + 24);
      const float2 w4 = *(const float2*)(wp + 32);
      const float2 w5 = *(const float2*)(wp + 40);
      const float2 w6 = *(const float2*)(wp + 48);
      const float2 w7 = *(const float2*)(wp + 56);
      a0 += x0.x * w0.x; a1 += x0.x * w0.y;
      a0 += x0.y * w1.x; a1 += x0.y * w1.y;
      a0 += x0.z * w2.x; a1 += x0.z * w2.y;
      a0 += x0.w * w3.x; a1 += x0.w * w3.y;
      a0 += x1.x * w4.x; a1 += x1.x * w4.y;
      a0 += x1.y * w5.x; a1 += x1.y * w5.y;
      a0 += x1.z * w6.x; a1 += x1.z * w6.y;
      a0 += x1.w * w7.x; a1 += x1.w * w7.y;
    }
  }

  const float nm = norm[node];
  const int o = b * 8 + op;
  float* outp = out + ((size_t)node << 7) + o;
  float2 prev = *(const float2*)outp;
  float2 res;
  res.x = fmaxf(prev.x + a0 * nm, 0.f);
  res.y = fmaxf(prev.y + a1 * nm, 0.f);
  *(float2*)outp = res;
}

__global__ __launch_bounds__(256) void edge_msg(
    const float* __restrict__ h, const float* __restrict__ norm,
    const float* __restrict__ weight, const int* __restrict__ src,
    const int* __restrict__ dst, const int* __restrict__ etype,
    float* out, int E) {
  const int wave = (int)((blockIdx.x * blockDim.x + threadIdx.x) >> 6);
  const int lane = threadIdx.x & 63;
  if (wave >= E) return;

  const int s = src[wave];
  const int d = dst[wave];
  const int r = etype[wave];
  const float nrm = norm[d];

  const int b = lane >> 2;
  const int op = (lane & 3) * 2;

  const float* xp = h + (size_t)s * IN_FEAT + b * 8;
  const float4 x0 = ((const float4*)xp)[0];
  const float4 x1 = ((const float4*)xp)[1];
  float x[8] = {x0.x, x0.y, x0.z, x0.w, x1.x, x1.y, x1.z, x1.w};

  const float* wp = weight + (size_t)r * 1024 + b * 64 + op;
  float a0 = 0.f, a1 = 0.f;
  #pragma unroll
  for (int i = 0; i < 8; ++i) {
    const float2 w = *(const float2*)(wp + i * 8);
    a0 += x[i] * w.x;
    a1 += x[i] * w.y;
  }

  const int o = b * 8 + op;
  float* outp = out + (size_t)d * OUT_FEAT + o;
  atomicAdd(outp, a0 * nrm);
  atomicAdd(outp + 1, a1 * nrm);
}

__global__ __launch_bounds__(256) void relu_k(float* __restrict__ out, int n4) {
  const int i = blockIdx.x * blockDim.x + threadIdx.x;
  if (i < n4) {
    float4 v = ((const float4*)out)[i];
    v.x = fmaxf(v.x, 0.f);
    v.y = fmaxf(v.y, 0.f);
    v.z = fmaxf(v.z, 0.f);
    v.w = fmaxf(v.w, 0.f);
    ((float4*)out)[i] = v;
  }
}

extern "C" void kernel_launch(void* const* d_in, const int* in_sizes, int n_in,
                              void* d_out, int out_size, void* d_ws, size_t ws_size,
                              hipStream_t stream) {
  const float* h    = (const float*)d_in[0];
  const float* norm = (const float*)d_in[1];
  const float* w    = (const float*)d_in[2];
  const float* lw   = (const float*)d_in[3];
  const int* src    = (const int*)d_in[4];
  const int* dst    = (const int*)d_in[5];
  const int* etype  = (const int*)d_in[6];
  float* out = (float*)d_out;

  const int N = in_sizes[1];            // norm has N elements
  const int E = in_sizes[4];            // src has E elements
  const int R = in_sizes[2] / 1024;     // weight rows
  const int nblk = (N + SCAN_CHUNK - 1) / SCAN_CHUNK;

  // ws layout: srcet[E] int2 | cnt[N] | pos[N] | bsum[128] (legacy pad) |
  //            h16[N*128] bf16 | w16[R*1024] bf16
  const size_t nb_bsum = (size_t)((nblk < 128) ? 128 : nblk);
  const size_t off_cnt  = (size_t)E * 8;
  const size_t off_pos  = off_cnt + (size_t)N * 4;
  const size_t off_bsum = off_pos + (size_t)N * 4;
  size_t off_h16 = off_bsum + nb_bsum * 4;
  off_h16 = (off_h16 + 15) & ~(size_t)15;
  const size_t off_w16 = off_h16 + (size_t)N * IN_FEAT * 2;
  const size_t need_full = off_w16 + (size_t)R * 1024 * 2;
  const size_t need_sort = off_bsum + nb_bsum * 4;

  if (ws_size >= need_full) {
    char* wsb = (char*)d_ws;
    int2* srcet = (int2*)wsb;
    int* cnt  = (int*)(wsb + off_cnt);
    int* pos  = (int*)(wsb + off_pos);
    unsigned short* h16 = (unsigned short*)(wsb + off_h16);
    unsigned short* w16 = (unsigned short*)(wsb + off_w16);

    hipMemsetAsync(cnt, 0, (size_t)N * 4, stream);

    // fused prologue: wpack | hpack | gemm(MFMA, self-staged lw) | hist
    const int htotal8 = N * IN_FEAT / 8;
    const int bw  = R;
    const int bh  = (htotal8 + 255) / 256;
    const int bg  = ((N + 63) / 64) * 4;
    const int bhist = (E + 1023) / 1024;
    k_prep<<<bw + bh + bg + bhist, 256, 0, stream>>>(
        w, w16, h, (uint4*)h16, htotal8, lw, dst, cnt, E, out, N, bw, bh, bg);

    // offsets (self-computed chunk prefix) + scatter (4 edges/thread)
    k_offsets_sp<<<nblk, 256, 0, stream>>>(cnt, pos, N);
    k_scatter<<<(E + 1023) / 1024, 256, 0, stream>>>(src, dst, etype, pos,
                                                     srcet, E);

    // one wave per node; fused norm + self-loop add + relu
    agg_bf16<<<(N + 3) / 4, 256, 0, stream>>>(h16, norm, w16, pos, cnt, srcet,
                                              out, N);
  } else if (ws_size >= need_sort) {
    char* wsb = (char*)d_ws;
    int2* srcet = (int2*)wsb;
    int* cnt  = (int*)(wsb + off_cnt);
    int* pos  = (int*)(wsb + off_pos);

    selfloop_gemm<<<512, 256, 0, stream>>>(h, lw, out, N);
    hipMemsetAsync(cnt, 0, (size_t)N * 4, stream);
    k_hist<<<(E + 255) / 256, 256, 0, stream>>>(dst, cnt, E);
    k_offsets_sp<<<nblk, 256, 0, stream>>>(cnt, pos, N);
    k_scatter<<<(E + 1023) / 1024, 256, 0, stream>>>(src, dst, etype, pos,
                                                     srcet, E);
    agg<<<(N + 3) / 4, 256, 0, stream>>>(h, norm, w, pos, cnt, srcet, out, N);
  } else {
    selfloop_gemm<<<512, 256, 0, stream>>>(h, lw, out, N);
    edge_msg<<<(E + 3) / 4, 256, 0, stream>>>(h, norm, w, src, dst, etype, out, E);
    const int n4 = N * OUT_FEAT / 4;
    relu_k<<<(n4 + 255) / 256, 256, 0, stream>>>(out, n4);
  }
}

// Round 12
// 160.478 us; speedup vs baseline: 2.0479x; 1.0208x over previous
//
#include <hip/hip_runtime.h>
#include <hip/hip_bf16.h>

// RGCN layer: out = relu( segment_sum(blockdiag_msg) * norm + h @ loop_weight )
//
// Inputs (setup_inputs order):
//   0: h           [N,128]  f32
//   1: norm        [N,1]    f32
//   2: weight      [R,1024] f32   (R x NB(16) x SI(8) x SO(8))
//   3: loop_weight [128,128] f32
//   4: src         [E] i32
//   5: dst         [E] i32
//   6: etype       [E] i32
// Output: [N,128] f32
//
// Round-11: r10's k_prep-gemm fusion regressed (slow f32/scalar-convert gemm
// variant, forced by the lwT dependency). Recombination of proven-fast parts:
// k_prep = r7 form (wpack|hpack|lwpack|hist); the FAST bf16 h16/lwT MFMA gemm
// rides in the k_offsets dispatch (prep's outputs are ready; offsets alone is
// only 98 blocks). Chain: memset, k_prep, k_off_gemm(offsets|gemm),
// k_scatter, agg_bf16 = 5 dispatches. agg = r7 proven 58us form, untouched.

#define IN_FEAT 128
#define OUT_FEAT 128
#define SCAN_CHUNK 512

using short8  = __attribute__((ext_vector_type(8))) short;
using float4v = __attribute__((ext_vector_type(4))) float;

__device__ inline float blo(unsigned u) { return __uint_as_float(u << 16); }
__device__ inline float bhi(unsigned u) { return __uint_as_float(u & 0xffff0000u); }
__device__ inline unsigned short f2bf(float f) {
  __hip_bfloat16 b = __float2bfloat16(f);
  return *reinterpret_cast<unsigned short*>(&b);
}

// dword = 2 packed bf16; returns c + x.lo*w.lo + x.hi*w.hi
__device__ inline float dot2bf(unsigned x, unsigned w, float c) {
#if __has_builtin(__builtin_amdgcn_fdot2_f32_bf16)
  typedef __bf16 bf16x2 __attribute__((ext_vector_type(2)));
  return __builtin_amdgcn_fdot2_f32_bf16(__builtin_bit_cast(bf16x2, x),
                                         __builtin_bit_cast(bf16x2, w), c, false);
#else
  return c + blo(x) * blo(w) + bhi(x) * bhi(w);
#endif
}

// ---------------------------------------------------------------------------
// Fused prologue (r7 proven): [wpack | hpack | lwpack | hist(x4)].
// wpack: one block per relation r; LDS-staged coalesced bf16 pack, dot2 layout
//   w16[r][b*64+opp*16+j*8+i] = bf16(w[r][b*64+i*8+opp*2+j]).
// hpack: h16 row-major bf16 copy of h (uint4 in/out).
// lwpack: lwT[o*128 + k] = bf16(lw[k*128 + o])  (col-major for MFMA B-frags).
// hist: cnt[dst[e]]++ with int4 loads, 4 edges/thread (cnt pre-zeroed).
// ---------------------------------------------------------------------------
__global__ __launch_bounds__(256) void k_prep(
    const float* __restrict__ w, unsigned short* __restrict__ w16,
    const float* __restrict__ h, uint4* __restrict__ h16p, int htotal8,
    const float* __restrict__ lw, unsigned short* __restrict__ lwT,
    const int* __restrict__ dst, int* __restrict__ cnt, int E,
    int bw, int bh, int blw) {
  __shared__ float srow[1024];
  const int bid = blockIdx.x;
  if (bid < bw) {  // bw == R; one relation per block
    const float* wr = w + ((size_t)bid << 10);
    ((float4*)srow)[threadIdx.x] = ((const float4*)wr)[threadIdx.x];
    __syncthreads();
    const int d0 = threadIdx.x * 4;
    unsigned short o4[4];
    #pragma unroll
    for (int k = 0; k < 4; ++k) {
      const int d = d0 + k;
      const int b = d >> 6;
      const int q = d & 63;
      const int opp = q >> 4;
      const int tt = q & 15;
      const int jj = tt >> 3;
      const int ii = tt & 7;
      o4[k] = f2bf(srow[b * 64 + ii * 8 + opp * 2 + jj]);
    }
    *(uint2*)(w16 + ((size_t)bid << 10) + d0) =
        make_uint2((unsigned)o4[0] | ((unsigned)o4[1] << 16),
                   (unsigned)o4[2] | ((unsigned)o4[3] << 16));
  } else if (bid < bw + bh) {
    const int t = (bid - bw) * 256 + threadIdx.x;
    if (t < htotal8) {
      const float4 a = ((const float4*)h)[2 * t];
      const float4 b = ((const float4*)h)[2 * t + 1];
      uint4 o;
      o.x = (unsigned)f2bf(a.x) | ((unsigned)f2bf(a.y) << 16);
      o.y = (unsigned)f2bf(a.z) | ((unsigned)f2bf(a.w) << 16);
      o.z = (unsigned)f2bf(b.x) | ((unsigned)f2bf(b.y) << 16);
      o.w = (unsigned)f2bf(b.z) | ((unsigned)f2bf(b.w) << 16);
      h16p[t] = o;
    }
  } else if (bid < bw + bh + blw) {
    const int idx = (bid - bw - bh) * 256 + threadIdx.x;
    if (idx < IN_FEAT * OUT_FEAT) {
      const int o = idx >> 7;
      const int k = idx & 127;
      lwT[idx] = f2bf(lw[k * 128 + o]);
    }
  } else {
    const int e0 = ((bid - bw - bh - blw) * 256 + threadIdx.x) * 4;
    if (e0 + 3 < E) {
      const int4 d4 = *(const int4*)(dst + e0);
      atomicAdd(&cnt[d4.x], 1);
      atomicAdd(&cnt[d4.y], 1);
      atomicAdd(&cnt[d4.z], 1);
      atomicAdd(&cnt[d4.w], 1);
    } else {
      for (int e = e0; e < E; ++e) atomicAdd(&cnt[dst[e]], 1);
    }
  }
}

// ---------------------------------------------------------------------------
// Fused: [offsets_sp | gemm] by blockIdx range (one dispatch).
// offsets_sp (blocks 0..nblk): per-chunk exclusive scan -> pos; block vb sums
//   cnt[0..vb*512) directly for its prefix (validated r9/r10).
// gemm (blocks nblk..): out = h16 @ lw via MFMA, bf16 h16/lwT (r7-fast form).
//   Wave handles 16 rows x 128 cols; C mapping row=(lane>>4)*4+r, col=lane&15.
// ---------------------------------------------------------------------------
__global__ __launch_bounds__(256) void k_off_gemm(
    const int* __restrict__ cnt, int* __restrict__ pos, int N,
    const unsigned short* __restrict__ h16, const unsigned short* __restrict__ lwT,
    float* __restrict__ out, int nblk) {
  if ((int)blockIdx.x < nblk) {
    __shared__ int s[256];
    __shared__ int sbase;
    const int t = threadIdx.x;
    const int vb = blockIdx.x;
    {
      const int lim = vb * SCAN_CHUNK;
      int acc = 0;
      for (int i = t; i < lim; i += 256) acc += cnt[i];
      s[t] = acc;
      __syncthreads();
      for (int d = 128; d > 0; d >>= 1) {
        if (t < d) s[t] += s[t + d];
        __syncthreads();
      }
      if (t == 0) sbase = s[0];
      __syncthreads();
    }
    const int base = vb * SCAN_CHUNK;
    const int i0 = base + 2 * t;
    const int i1 = i0 + 1;
    const int c0 = (i0 < N) ? cnt[i0] : 0;
    const int c1 = (i1 < N) ? cnt[i1] : 0;
    const int pair = c0 + c1;
    s[t] = pair;
    __syncthreads();
    #pragma unroll
    for (int d = 1; d < 256; d <<= 1) {
      int v = (t >= d) ? s[t - d] : 0;
      __syncthreads();
      s[t] += v;
      __syncthreads();
    }
    const int ex = s[t] - pair + sbase;  // exclusive prefix
    if (i0 < N) pos[i0] = ex;
    if (i1 < N) pos[i1] = ex + c0;
  } else {
    const int gb = blockIdx.x - nblk;
    const int wid = threadIdx.x >> 6;
    const int lane = threadIdx.x & 63;
    const int row0 = gb * 64 + wid * 16;
    if (row0 >= N) return;  // whole-wave exit; no barriers in this branch
    const int m = lane & 15;
    const int kg = (lane >> 4) * 8;
    const int arow = min(row0 + m, N - 1);

    float4v acc[8];
    #pragma unroll
    for (int nt = 0; nt < 8; ++nt) acc[nt] = (float4v){0.f, 0.f, 0.f, 0.f};

    const unsigned short* ap = h16 + (size_t)arow * 128 + kg;
    const unsigned short* bp = lwT + (size_t)m * 128 + kg;

    #pragma unroll
    for (int kc = 0; kc < 4; ++kc) {
      const short8 a = *(const short8*)(ap + kc * 32);
      #pragma unroll
      for (int nt = 0; nt < 8; ++nt) {
        const short8 b = *(const short8*)(bp + nt * 2048 + kc * 32);
        acc[nt] = __builtin_amdgcn_mfma_f32_16x16x32_bf16(a, b, acc[nt], 0, 0, 0);
      }
    }

    const int crow = row0 + (lane >> 4) * 4;
    #pragma unroll
    for (int nt = 0; nt < 8; ++nt) {
      #pragma unroll
      for (int r = 0; r < 4; ++r) {
        const int row = crow + r;
        if (row < N) out[(size_t)row * 128 + nt * 16 + m] = acc[nt][r];
      }
    }
  }
}

// 4 edges/thread, int4 loads.
__global__ __launch_bounds__(256) void k_scatter(
    const int* __restrict__ src, const int* __restrict__ dst,
    const int* __restrict__ etype, int* __restrict__ pos,
    int2* __restrict__ srcet, int E) {
  const int e0 = (blockIdx.x * blockDim.x + threadIdx.x) * 4;
  if (e0 + 3 < E) {
    const int4 s4 = *(const int4*)(src + e0);
    const int4 d4 = *(const int4*)(dst + e0);
    const int4 t4 = *(const int4*)(etype + e0);
    int p;
    p = atomicAdd(&pos[d4.x], 1); srcet[p] = make_int2(s4.x, t4.x);
    p = atomicAdd(&pos[d4.y], 1); srcet[p] = make_int2(s4.y, t4.y);
    p = atomicAdd(&pos[d4.z], 1); srcet[p] = make_int2(s4.z, t4.z);
    p = atomicAdd(&pos[d4.w], 1); srcet[p] = make_int2(s4.w, t4.w);
  } else {
    for (int e = e0; e < E; ++e) {
      const int p = atomicAdd(&pos[dst[e]], 1);
      srcet[p] = make_int2(src[e], etype[e]);
    }
  }
}

// ---------------------------------------------------------------------------
// bf16 aggregation (r7 proven, 58us): one wave per node; lane (b,opp) owns
// outputs o=b*8+opp*2, o+1. Per 4-edge group one 16B load fetches all 4
// edges' h rows (lane=(edge,chunk)), distributed via shfl; per edge
// 2 x 16B weight loads + 8 dot2. Epilogue prev/norm prefetched.
// out = relu(out + acc*norm)   (out holds loop_message from k_off_gemm).
// ---------------------------------------------------------------------------
__global__ __launch_bounds__(256) void agg_bf16(
    const unsigned short* __restrict__ h16, const float* __restrict__ norm,
    const unsigned short* __restrict__ w16, const int* __restrict__ pos,
    const int* __restrict__ cnt, const int2* __restrict__ srcet,
    float* __restrict__ out, int N) {
  const int node = (int)((blockIdx.x * blockDim.x + threadIdx.x) >> 6);
  const int lane = threadIdx.x & 63;
  if (node >= N) return;

  const int b = lane >> 2;
  const int opp = lane & 3;
  const int woff = b * 64 + opp * 16;  // ushort units
  const int o = b * 8 + opp * 2;

  const int num = cnt[node];
  const int end = pos[node];
  const int begin = end - num;

  float* outp = out + ((size_t)node << 7) + o;
  const float2 prev = *(const float2*)outp;
  const float nm = norm[node];

  float a0 = 0.f, a1 = 0.f;

  for (int base = 0; base < num; base += 64) {
    const int cn = min(64, num - base);
    const int2 my = srcet[begin + base + min(lane, cn - 1)];
    for (int i4 = 0; i4 < cn; i4 += 4) {
      const int gl = min(i4 + (lane >> 4), cn - 1);
      const int sg = __shfl(my.x, gl);
      const uint4 xq =
          *(const uint4*)(h16 + ((size_t)sg << 7) + (lane & 15) * 8);
      const int nin = min(4, cn - i4);
      #pragma unroll 4
      for (int u = 0; u < nin; ++u) {
        const int r = __shfl(my.y, i4 + u);
        const int sl = u * 16 + b;
        uint4 xv;
        xv.x = __shfl(xq.x, sl);
        xv.y = __shfl(xq.y, sl);
        xv.z = __shfl(xq.z, sl);
        xv.w = __shfl(xq.w, sl);
        const unsigned short* wp = w16 + ((size_t)r << 10) + woff;
        const uint4 wa = *(const uint4*)(wp);
        const uint4 wb = *(const uint4*)(wp + 8);

        a0 = dot2bf(xv.x, wa.x, a0);
        a0 = dot2bf(xv.y, wa.y, a0);
        a0 = dot2bf(xv.z, wa.z, a0);
        a0 = dot2bf(xv.w, wa.w, a0);
        a1 = dot2bf(xv.x, wb.x, a1);
        a1 = dot2bf(xv.y, wb.y, a1);
        a1 = dot2bf(xv.z, wb.z, a1);
        a1 = dot2bf(xv.w, wb.w, a1);
      }
    }
  }

  float2 res;
  res.x = fmaxf(prev.x + a0 * nm, 0.f);
  res.y = fmaxf(prev.y + a1 * nm, 0.f);
  *(float2*)outp = res;
}

// ===========================================================================
// Fallback kernels (middle / minimal ws paths)
// ===========================================================================
__global__ __launch_bounds__(256) void k_hist(
    const int* __restrict__ dst, int* __restrict__ cnt, int E) {
  const int e = blockIdx.x * blockDim.x + threadIdx.x;
  if (e < E) atomicAdd(&cnt[dst[e]], 1);
}

__global__ __launch_bounds__(256) void k_offsets_sp(
    const int* __restrict__ cnt, int* __restrict__ pos, int N) {
  __shared__ int s[256];
  __shared__ int sbase;
  const int t = threadIdx.x;
  const int vb = blockIdx.x;
  {
    const int lim = vb * SCAN_CHUNK;
    int acc = 0;
    for (int i = t; i < lim; i += 256) acc += cnt[i];
    s[t] = acc;
    __syncthreads();
    for (int d = 128; d > 0; d >>= 1) {
      if (t < d) s[t] += s[t + d];
      __syncthreads();
    }
    if (t == 0) sbase = s[0];
    __syncthreads();
  }
  const int base = vb * SCAN_CHUNK;
  const int i0 = base + 2 * t;
  const int i1 = i0 + 1;
  const int c0 = (i0 < N) ? cnt[i0] : 0;
  const int c1 = (i1 < N) ? cnt[i1] : 0;
  const int pair = c0 + c1;
  s[t] = pair;
  __syncthreads();
  #pragma unroll
  for (int d = 1; d < 256; d <<= 1) {
    int v = (t >= d) ? s[t - d] : 0;
    __syncthreads();
    s[t] += v;
    __syncthreads();
  }
  const int ex = s[t] - pair + sbase;
  if (i0 < N) pos[i0] = ex;
  if (i1 < N) pos[i1] = ex + c0;
}

__global__ __launch_bounds__(256) void selfloop_gemm(
    const float* __restrict__ h, const float* __restrict__ lw,
    float* __restrict__ out, int n) {
  __shared__ float slw[IN_FEAT * OUT_FEAT];
  __shared__ float sh[32 * IN_FEAT];

  {
    const float4* s4 = (const float4*)lw;
    float4* d4 = (float4*)slw;
    for (int i = threadIdx.x; i < IN_FEAT * OUT_FEAT / 4; i += 256) d4[i] = s4[i];
  }

  const int cg_ = threadIdx.x & 31;
  const int rg = threadIdx.x >> 5;

  for (int base = blockIdx.x * 32; base < n; base += gridDim.x * 32) {
    const int nrows = min(32, n - base);
    __syncthreads();
    {
      const float4* hs = (const float4*)(h + (size_t)base * IN_FEAT);
      float4* sd = (float4*)sh;
      const int cnt = nrows * (IN_FEAT / 4);
      for (int i = threadIdx.x; i < cnt; i += 256) sd[i] = hs[i];
    }
    __syncthreads();

    float4 acc[4];
    #pragma unroll
    for (int j = 0; j < 4; ++j) acc[j] = make_float4(0.f, 0.f, 0.f, 0.f);

    #pragma unroll 4
    for (int k = 0; k < IN_FEAT; ++k) {
      const float4 w = ((const float4*)slw)[k * 32 + cg_];
      #pragma unroll
      for (int j = 0; j < 4; ++j) {
        const float hv = sh[(rg + 8 * j) * IN_FEAT + k];
        acc[j].x += hv * w.x;
        acc[j].y += hv * w.y;
        acc[j].z += hv * w.z;
        acc[j].w += hv * w.w;
      }
    }

    #pragma unroll
    for (int j = 0; j < 4; ++j) {
      const int r = rg + 8 * j;
      if (r < nrows) {
        ((float4*)(out + (size_t)(base + r) * OUT_FEAT))[cg_] = acc[j];
      }
    }
  }
}

__global__ __launch_bounds__(256) void agg(
    const float* __restrict__ h, const float* __restrict__ norm,
    const float* __restrict__ weight, const int* __restrict__ pos,
    const int* __restrict__ cnt, const int2* __restrict__ srcet,
    float* __restrict__ out, int N) {
  const int node = (int)((blockIdx.x * blockDim.x + threadIdx.x) >> 6);
  const int lane = threadIdx.x & 63;
  if (node >= N) return;

  const int b = lane >> 2;
  const int op = (lane & 3) * 2;
  const int boff = b * 64 + op;

  const int num = cnt[node];
  const int end = pos[node];
  const int begin = end - num;

  float a0 = 0.f, a1 = 0.f;

  for (int base = 0; base < num; base += 64) {
    const int cn = min(64, num - base);
    const int2 my = srcet[begin + base + min(lane, cn - 1)];
    #pragma unroll 2
    for (int i = 0; i < cn; ++i) {
      const int s = __shfl(my.x, i);
      const int r = __shfl(my.y, i);
      const float* xp = h + ((size_t)s << 7) + b * 8;
      const float4 x0 = ((const float4*)xp)[0];
      const float4 x1 = ((const float4*)xp)[1];
      const float* wp = weight + ((size_t)r << 10) + boff;
      const float2 w0 = *(const float2*)(wp);
      const float2 w1 = *(const float2*)(wp + 8);
      const float2 w2 = *(const float2*)(wp + 16);
      const float2 w3 = *(const float2*)(wp + 24);
      const float2 w4 = *(const float2*)(wp + 32);
      const float2 w5 = *(const float2*)(wp + 40);
      const float2 w6 = *(const float2*)(wp + 48);
      const float2 w7 = *(const float2*)(wp + 56);
      a0 += x0.x * w0.x; a1 += x0.x * w0.y;
      a0 += x0.y * w1.x; a1 += x0.y * w1.y;
      a0 += x0.z * w2.x; a1 += x0.z * w2.y;
      a0 += x0.w * w3.x; a1 += x0.w * w3.y;
      a0 += x1.x * w4.x; a1 += x1.x * w4.y;
      a0 += x1.y * w5.x; a1 += x1.y * w5.y;
      a0 += x1.z * w6.x; a1 += x1.z * w6.y;
      a0 += x1.w * w7.x; a1 += x1.w * w7.y;
    }
  }

  const float nm = norm[node];
  const int o = b * 8 + op;
  float* outp = out + ((size_t)node << 7) + o;
  float2 prev = *(const float2*)outp;
  float2 res;
  res.x = fmaxf(prev.x + a0 * nm, 0.f);
  res.y = fmaxf(prev.y + a1 * nm, 0.f);
  *(float2*)outp = res;
}

__global__ __launch_bounds__(256) void edge_msg(
    const float* __restrict__ h, const float* __restrict__ norm,
    const float* __restrict__ weight, const int* __restrict__ src,
    const int* __restrict__ dst, const int* __restrict__ etype,
    float* out, int E) {
  const int wave = (int)((blockIdx.x * blockDim.x + threadIdx.x) >> 6);
  const int lane = threadIdx.x & 63;
  if (wave >= E) return;

  const int s = src[wave];
  const int d = dst[wave];
  const int r = etype[wave];
  const float nrm = norm[d];

  const int b = lane >> 2;
  const int op = (lane & 3) * 2;

  const float* xp = h + (size_t)s * IN_FEAT + b * 8;
  const float4 x0 = ((const float4*)xp)[0];
  const float4 x1 = ((const float4*)xp)[1];
  float x[8] = {x0.x, x0.y, x0.z, x0.w, x1.x, x1.y, x1.z, x1.w};

  const float* wp = weight + (size_t)r * 1024 + b * 64 + op;
  float a0 = 0.f, a1 = 0.f;
  #pragma unroll
  for (int i = 0; i < 8; ++i) {
    const float2 w = *(const float2*)(wp + i * 8);
    a0 += x[i] * w.x;
    a1 += x[i] * w.y;
  }

  const int o = b * 8 + op;
  float* outp = out + (size_t)d * OUT_FEAT + o;
  atomicAdd(outp, a0 * nrm);
  atomicAdd(outp + 1, a1 * nrm);
}

__global__ __launch_bounds__(256) void relu_k(float* __restrict__ out, int n4) {
  const int i = blockIdx.x * blockDim.x + threadIdx.x;
  if (i < n4) {
    float4 v = ((const float4*)out)[i];
    v.x = fmaxf(v.x, 0.f);
    v.y = fmaxf(v.y, 0.f);
    v.z = fmaxf(v.z, 0.f);
    v.w = fmaxf(v.w, 0.f);
    ((float4*)out)[i] = v;
  }
}

extern "C" void kernel_launch(void* const* d_in, const int* in_sizes, int n_in,
                              void* d_out, int out_size, void* d_ws, size_t ws_size,
                              hipStream_t stream) {
  const float* h    = (const float*)d_in[0];
  const float* norm = (const float*)d_in[1];
  const float* w    = (const float*)d_in[2];
  const float* lw   = (const float*)d_in[3];
  const int* src    = (const int*)d_in[4];
  const int* dst    = (const int*)d_in[5];
  const int* etype  = (const int*)d_in[6];
  float* out = (float*)d_out;

  const int N = in_sizes[1];            // norm has N elements
  const int E = in_sizes[4];            // src has E elements
  const int R = in_sizes[2] / 1024;     // weight rows
  const int nblk = (N + SCAN_CHUNK - 1) / SCAN_CHUNK;

  // ws layout: srcet[E] int2 | cnt[N] | pos[N] | pad[128] |
  //            h16[N*128] bf16 | w16[R*1024] bf16 | lwT[128*128] bf16
  const size_t nb_bsum = (size_t)((nblk < 128) ? 128 : nblk);
  const size_t off_cnt  = (size_t)E * 8;
  const size_t off_pos  = off_cnt + (size_t)N * 4;
  const size_t off_bsum = off_pos + (size_t)N * 4;
  size_t off_h16 = off_bsum + nb_bsum * 4;
  off_h16 = (off_h16 + 15) & ~(size_t)15;
  const size_t off_w16 = off_h16 + (size_t)N * IN_FEAT * 2;
  const size_t off_lwT = off_w16 + (size_t)R * 1024 * 2;
  const size_t need_full = off_lwT + (size_t)IN_FEAT * OUT_FEAT * 2;
  const size_t need_sort = off_bsum + nb_bsum * 4;

  if (ws_size >= need_full) {
    char* wsb = (char*)d_ws;
    int2* srcet = (int2*)wsb;
    int* cnt  = (int*)(wsb + off_cnt);
    int* pos  = (int*)(wsb + off_pos);
    unsigned short* h16 = (unsigned short*)(wsb + off_h16);
    unsigned short* w16 = (unsigned short*)(wsb + off_w16);
    unsigned short* lwT = (unsigned short*)(wsb + off_lwT);

    hipMemsetAsync(cnt, 0, (size_t)N * 4, stream);

    // fused prologue: wpack (1 block/relation) + hpack + lwpack + hist (x4)
    const int htotal8 = N * IN_FEAT / 8;
    const int bw  = R;
    const int bh  = (htotal8 + 255) / 256;
    const int blw = (IN_FEAT * OUT_FEAT + 255) / 256;
    const int bhist = (E + 1023) / 1024;
    k_prep<<<bw + bh + blw + bhist, 256, 0, stream>>>(
        w, w16, h, (uint4*)h16, htotal8, lw, lwT, dst, cnt, E, bw, bh, blw);

    // fused: offsets (self prefix) + fast bf16 MFMA gemm (out = loop_message)
    const int gemm_blocks = (N + 63) / 64;
    k_off_gemm<<<nblk + gemm_blocks, 256, 0, stream>>>(
        cnt, pos, N, h16, lwT, out, nblk);

    // scatter (4 edges/thread)
    k_scatter<<<(E + 1023) / 1024, 256, 0, stream>>>(src, dst, etype, pos,
                                                     srcet, E);

    // one wave per node; fused norm + self-loop add + relu
    agg_bf16<<<(N + 3) / 4, 256, 0, stream>>>(h16, norm, w16, pos, cnt, srcet,
                                              out, N);
  } else if (ws_size >= need_sort) {
    char* wsb = (char*)d_ws;
    int2* srcet = (int2*)wsb;
    int* cnt  = (int*)(wsb + off_cnt);
    int* pos  = (int*)(wsb + off_pos);

    selfloop_gemm<<<512, 256, 0, stream>>>(h, lw, out, N);
    hipMemsetAsync(cnt, 0, (size_t)N * 4, stream);
    k_hist<<<(E + 255) / 256, 256, 0, stream>>>(dst, cnt, E);
    k_offsets_sp<<<nblk, 256, 0, stream>>>(cnt, pos, N);
    k_scatter<<<(E + 1023) / 1024, 256, 0, stream>>>(src, dst, etype, pos,
                                                     srcet, E);
    agg<<<(N + 3) / 4, 256, 0, stream>>>(h, norm, w, pos, cnt, srcet, out, N);
  } else {
    selfloop_gemm<<<512, 256, 0, stream>>>(h, lw, out, N);
    edge_msg<<<(E + 3) / 4, 256, 0, stream>>>(h, norm, w, src, dst, etype, out, E);
    const int n4 = N * OUT_FEAT / 4;
    relu_k<<<(n4 + 255) / 256, 256, 0, stream>>>(out, n4);
  }
}

// Round 13
// 146.142 us; speedup vs baseline: 2.2488x; 1.0981x over previous
//
#include <hip/hip_runtime.h>
#include <hip/hip_bf16.h>

// RGCN layer: out = relu( segment_sum(blockdiag_msg) * norm + h @ loop_weight )
//
// Inputs (setup_inputs order):
//   0: h           [N,128]  f32
//   1: norm        [N,1]    f32
//   2: weight      [R,1024] f32   (R x NB(16) x SI(8) x SO(8))
//   3: loop_weight [128,128] f32
//   4: src         [E] i32
//   5: dst         [E] i32
//   6: etype       [E] i32
// Output: [N,128] f32
//
// Round-12: REVERT to the round-7 configuration (best measured: 148.4us).
// r8-r11 falsified every structural alternative: cooperative grid.sync
// (~80-100us/sync on 8-XCD, 400us), gemm-into-agg (TLP collapse, 170us),
// gemm-into-prep (slow gemm variant, 164us), gemm-into-offsets (160us).
// agg_bf16 = 58.3us is the L2 random-gather floor (bracketed by r4/r5/r6/r7
// probes); prologue = 4 serial sort phases; boundary cost is insensitive to
// dispatch count. This is the proven-fast combination of all components.

#define IN_FEAT 128
#define OUT_FEAT 128
#define SCAN_CHUNK 512

using short8  = __attribute__((ext_vector_type(8))) short;
using float4v = __attribute__((ext_vector_type(4))) float;

__device__ inline float blo(unsigned u) { return __uint_as_float(u << 16); }
__device__ inline float bhi(unsigned u) { return __uint_as_float(u & 0xffff0000u); }
__device__ inline unsigned short f2bf(float f) {
  __hip_bfloat16 b = __float2bfloat16(f);
  return *reinterpret_cast<unsigned short*>(&b);
}

// dword = 2 packed bf16; returns c + x.lo*w.lo + x.hi*w.hi
__device__ inline float dot2bf(unsigned x, unsigned w, float c) {
#if __has_builtin(__builtin_amdgcn_fdot2_f32_bf16)
  typedef __bf16 bf16x2 __attribute__((ext_vector_type(2)));
  return __builtin_amdgcn_fdot2_f32_bf16(__builtin_bit_cast(bf16x2, x),
                                         __builtin_bit_cast(bf16x2, w), c, false);
#else
  return c + blo(x) * blo(w) + bhi(x) * bhi(w);
#endif
}

// ---------------------------------------------------------------------------
// Fused prologue: [wpack | hpack | lwpack | hist(x4)] by blockIdx range.
// wpack: one block per relation r. Stage w row (4KB f32) in LDS coalesced,
//   write w16[r][b*64+opp*16+j*8+i] = bf16(w[r][b*64+i*8+opp*2+j]) coalesced.
// hpack: h16 row-major bf16 copy of h (uint4 in/out).
// lwpack: lwT[o*128 + k] = bf16(lw[k*128 + o])  (col-major for MFMA B-frags).
// hist: cnt[dst[e]]++ with int4 loads, 4 edges/thread (cnt pre-zeroed).
// ---------------------------------------------------------------------------
__global__ __launch_bounds__(256) void k_prep(
    const float* __restrict__ w, unsigned short* __restrict__ w16,
    const float* __restrict__ h, uint4* __restrict__ h16p, int htotal8,
    const float* __restrict__ lw, unsigned short* __restrict__ lwT,
    const int* __restrict__ dst, int* __restrict__ cnt, int E,
    int bw, int bh, int blw) {
  __shared__ float srow[1024];
  const int bid = blockIdx.x;
  if (bid < bw) {  // bw == R; one relation per block
    const float* wr = w + ((size_t)bid << 10);
    ((float4*)srow)[threadIdx.x] = ((const float4*)wr)[threadIdx.x];
    __syncthreads();
    const int d0 = threadIdx.x * 4;
    unsigned short o4[4];
    #pragma unroll
    for (int k = 0; k < 4; ++k) {
      const int d = d0 + k;
      const int b = d >> 6;
      const int q = d & 63;
      const int opp = q >> 4;
      const int tt = q & 15;
      const int jj = tt >> 3;
      const int ii = tt & 7;
      o4[k] = f2bf(srow[b * 64 + ii * 8 + opp * 2 + jj]);
    }
    *(uint2*)(w16 + ((size_t)bid << 10) + d0) =
        make_uint2((unsigned)o4[0] | ((unsigned)o4[1] << 16),
                   (unsigned)o4[2] | ((unsigned)o4[3] << 16));
  } else if (bid < bw + bh) {
    const int t = (bid - bw) * 256 + threadIdx.x;
    if (t < htotal8) {
      const float4 a = ((const float4*)h)[2 * t];
      const float4 b = ((const float4*)h)[2 * t + 1];
      uint4 o;
      o.x = (unsigned)f2bf(a.x) | ((unsigned)f2bf(a.y) << 16);
      o.y = (unsigned)f2bf(a.z) | ((unsigned)f2bf(a.w) << 16);
      o.z = (unsigned)f2bf(b.x) | ((unsigned)f2bf(b.y) << 16);
      o.w = (unsigned)f2bf(b.z) | ((unsigned)f2bf(b.w) << 16);
      h16p[t] = o;
    }
  } else if (bid < bw + bh + blw) {
    const int idx = (bid - bw - bh) * 256 + threadIdx.x;
    if (idx < IN_FEAT * OUT_FEAT) {
      const int o = idx >> 7;
      const int k = idx & 127;
      lwT[idx] = f2bf(lw[k * 128 + o]);
    }
  } else {
    const int e0 = ((bid - bw - bh - blw) * 256 + threadIdx.x) * 4;
    if (e0 + 3 < E) {
      const int4 d4 = *(const int4*)(dst + e0);
      atomicAdd(&cnt[d4.x], 1);
      atomicAdd(&cnt[d4.y], 1);
      atomicAdd(&cnt[d4.z], 1);
      atomicAdd(&cnt[d4.w], 1);
    } else {
      for (int e = e0; e < E; ++e) atomicAdd(&cnt[dst[e]], 1);
    }
  }
}

// ---------------------------------------------------------------------------
// Fused: [self-loop MFMA GEMM | chunksum] by blockIdx range.
// GEMM: out = h16 @ lw (bf16 in, f32 out).  chunksum: bsum[c] = sum cnt.
// ---------------------------------------------------------------------------
__global__ __launch_bounds__(256) void k_gemm_sum(
    const unsigned short* __restrict__ h16, const unsigned short* __restrict__ lwT,
    float* __restrict__ out, int N,
    const int* __restrict__ cnt, int* __restrict__ bsum, int gemm_blocks) {
  if (blockIdx.x < gemm_blocks) {
    const int wid = threadIdx.x >> 6;
    const int lane = threadIdx.x & 63;
    const int row0 = blockIdx.x * 64 + wid * 16;
    if (row0 >= N) return;
    const int m = lane & 15;
    const int kg = (lane >> 4) * 8;
    const int arow = min(row0 + m, N - 1);

    float4v acc[8];
    #pragma unroll
    for (int nt = 0; nt < 8; ++nt) acc[nt] = (float4v){0.f, 0.f, 0.f, 0.f};

    const unsigned short* ap = h16 + (size_t)arow * 128 + kg;
    const unsigned short* bp = lwT + (size_t)m * 128 + kg;

    #pragma unroll
    for (int kc = 0; kc < 4; ++kc) {
      const short8 a = *(const short8*)(ap + kc * 32);
      #pragma unroll
      for (int nt = 0; nt < 8; ++nt) {
        const short8 b = *(const short8*)(bp + nt * 2048 + kc * 32);
        acc[nt] = __builtin_amdgcn_mfma_f32_16x16x32_bf16(a, b, acc[nt], 0, 0, 0);
      }
    }

    const int crow = row0 + (lane >> 4) * 4;
    #pragma unroll
    for (int nt = 0; nt < 8; ++nt) {
      #pragma unroll
      for (int r = 0; r < 4; ++r) {
        const int row = crow + r;
        if (row < N) out[(size_t)row * 128 + nt * 16 + m] = acc[nt][r];
      }
    }
  } else {
    __shared__ int s[256];
    const int cb = blockIdx.x - gemm_blocks;
    const int t = threadIdx.x;
    const int base = cb * SCAN_CHUNK;
    int v = 0;
    const int i0 = base + t, i1 = base + 256 + t;
    if (i0 < N) v += cnt[i0];
    if (i1 < N) v += cnt[i1];
    s[t] = v;
    __syncthreads();
    for (int d = 128; d > 0; d >>= 1) {
      if (t < d) s[t] += s[t + d];
      __syncthreads();
    }
    if (t == 0) bsum[cb] = s[0];
  }
}

// standalone chunksum (fallback path)
__global__ __launch_bounds__(256) void k_chunksum(
    const int* __restrict__ cnt, int* __restrict__ bsum, int N) {
  __shared__ int s[256];
  const int t = threadIdx.x;
  const int base = blockIdx.x * SCAN_CHUNK;
  int v = 0;
  int i0 = base + t, i1 = base + 256 + t;
  if (i0 < N) v += cnt[i0];
  if (i1 < N) v += cnt[i1];
  s[t] = v;
  __syncthreads();
  for (int d = 128; d > 0; d >>= 1) {
    if (t < d) s[t] += s[t + d];
    __syncthreads();
  }
  if (t == 0) bsum[blockIdx.x] = s[0];
}

__global__ __launch_bounds__(256) void k_hist(
    const int* __restrict__ dst, int* __restrict__ cnt, int E) {
  const int e = blockIdx.x * blockDim.x + threadIdx.x;
  if (e < E) atomicAdd(&cnt[dst[e]], 1);
}

// ---------------------------------------------------------------------------
// Per-chunk exclusive scan writing pos; each block derives its own chunk
// prefix from bsum with a strided wave-0 reduction.
// ---------------------------------------------------------------------------
__global__ __launch_bounds__(256) void k_offsets(
    const int* __restrict__ cnt, const int* __restrict__ bsum,
    int* __restrict__ pos, int N) {
  __shared__ int s[256];
  __shared__ int sbase;
  const int t = threadIdx.x;
  if (t < 64) {
    int acc = 0;
    for (int j = t; j < (int)blockIdx.x; j += 64) acc += bsum[j];
    #pragma unroll
    for (int d = 1; d < 64; d <<= 1) acc += __shfl_xor(acc, d);
    if (t == 0) sbase = acc;
  }
  const int base = blockIdx.x * SCAN_CHUNK;
  const int i0 = base + 2 * t;
  const int i1 = i0 + 1;
  const int c0 = (i0 < N) ? cnt[i0] : 0;
  const int c1 = (i1 < N) ? cnt[i1] : 0;
  const int pair = c0 + c1;
  s[t] = pair;
  __syncthreads();
  #pragma unroll
  for (int d = 1; d < 256; d <<= 1) {
    int v = (t >= d) ? s[t - d] : 0;
    __syncthreads();
    s[t] += v;
    __syncthreads();
  }
  const int ex = s[t] - pair + sbase;
  if (i0 < N) pos[i0] = ex;
  if (i1 < N) pos[i1] = ex + c0;
}

// 4 edges/thread, int4 loads.
__global__ __launch_bounds__(256) void k_scatter(
    const int* __restrict__ src, const int* __restrict__ dst,
    const int* __restrict__ etype, int* __restrict__ pos,
    int2* __restrict__ srcet, int E) {
  const int e0 = (blockIdx.x * blockDim.x + threadIdx.x) * 4;
  if (e0 + 3 < E) {
    const int4 s4 = *(const int4*)(src + e0);
    const int4 d4 = *(const int4*)(dst + e0);
    const int4 t4 = *(const int4*)(etype + e0);
    int p;
    p = atomicAdd(&pos[d4.x], 1); srcet[p] = make_int2(s4.x, t4.x);
    p = atomicAdd(&pos[d4.y], 1); srcet[p] = make_int2(s4.y, t4.y);
    p = atomicAdd(&pos[d4.z], 1); srcet[p] = make_int2(s4.z, t4.z);
    p = atomicAdd(&pos[d4.w], 1); srcet[p] = make_int2(s4.w, t4.w);
  } else {
    for (int e = e0; e < E; ++e) {
      const int p = atomicAdd(&pos[dst[e]], 1);
      srcet[p] = make_int2(src[e], etype[e]);
    }
  }
}

// ---------------------------------------------------------------------------
// bf16 aggregation (r7 proven, 58us): one wave per node; lane (b,opp) owns
// outputs o=b*8+opp*2, o+1. Per 4-edge group one 16B load fetches all 4
// edges' h rows (lane=(edge,chunk)), distributed via shfl; per edge
// 2 x 16B weight loads + 8 dot2. Epilogue prev/norm prefetched.
// out = relu(out + acc*norm)   (out holds loop_message from k_gemm_sum).
// ---------------------------------------------------------------------------
__global__ __launch_bounds__(256) void agg_bf16(
    const unsigned short* __restrict__ h16, const float* __restrict__ norm,
    const unsigned short* __restrict__ w16, const int* __restrict__ pos,
    const int* __restrict__ cnt, const int2* __restrict__ srcet,
    float* __restrict__ out, int N) {
  const int node = (int)((blockIdx.x * blockDim.x + threadIdx.x) >> 6);
  const int lane = threadIdx.x & 63;
  if (node >= N) return;

  const int b = lane >> 2;
  const int opp = lane & 3;
  const int woff = b * 64 + opp * 16;  // ushort units
  const int o = b * 8 + opp * 2;

  const int num = cnt[node];
  const int end = pos[node];
  const int begin = end - num;

  // epilogue prefetch (out holds loop_message; gemm dispatch completed)
  float* outp = out + ((size_t)node << 7) + o;
  const float2 prev = *(const float2*)outp;
  const float nm = norm[node];

  float a0 = 0.f, a1 = 0.f;

  for (int base = 0; base < num; base += 64) {
    const int cn = min(64, num - base);
    const int2 my = srcet[begin + base + min(lane, cn - 1)];
    for (int i4 = 0; i4 < cn; i4 += 4) {
      // group h load: lane holds chunk (lane&15) of edge i4+(lane>>4)
      const int gl = min(i4 + (lane >> 4), cn - 1);
      const int sg = __shfl(my.x, gl);
      const uint4 xq =
          *(const uint4*)(h16 + ((size_t)sg << 7) + (lane & 15) * 8);
      const int nin = min(4, cn - i4);
      #pragma unroll 4
      for (int u = 0; u < nin; ++u) {
        const int r = __shfl(my.y, i4 + u);
        const int sl = u * 16 + b;
        uint4 xv;
        xv.x = __shfl(xq.x, sl);
        xv.y = __shfl(xq.y, sl);
        xv.z = __shfl(xq.z, sl);
        xv.w = __shfl(xq.w, sl);
        const unsigned short* wp = w16 + ((size_t)r << 10) + woff;
        const uint4 wa = *(const uint4*)(wp);
        const uint4 wb = *(const uint4*)(wp + 8);

        a0 = dot2bf(xv.x, wa.x, a0);
        a0 = dot2bf(xv.y, wa.y, a0);
        a0 = dot2bf(xv.z, wa.z, a0);
        a0 = dot2bf(xv.w, wa.w, a0);
        a1 = dot2bf(xv.x, wb.x, a1);
        a1 = dot2bf(xv.y, wb.y, a1);
        a1 = dot2bf(xv.z, wb.z, a1);
        a1 = dot2bf(xv.w, wb.w, a1);
      }
    }
  }

  float2 res;
  res.x = fmaxf(prev.x + a0 * nm, 0.f);
  res.y = fmaxf(prev.y + a1 * nm, 0.f);
  *(float2*)outp = res;
}

// ---------------------------------------------------------------------------
// f32 self-loop GEMM (fallback paths only).
// ---------------------------------------------------------------------------
__global__ __launch_bounds__(256) void selfloop_gemm(
    const float* __restrict__ h, const float* __restrict__ lw,
    float* __restrict__ out, int n) {
  __shared__ float slw[IN_FEAT * OUT_FEAT];
  __shared__ float sh[32 * IN_FEAT];

  {
    const float4* s4 = (const float4*)lw;
    float4* d4 = (float4*)slw;
    for (int i = threadIdx.x; i < IN_FEAT * OUT_FEAT / 4; i += 256) d4[i] = s4[i];
  }

  const int cg_ = threadIdx.x & 31;
  const int rg = threadIdx.x >> 5;

  for (int base = blockIdx.x * 32; base < n; base += gridDim.x * 32) {
    const int nrows = min(32, n - base);
    __syncthreads();
    {
      const float4* hs = (const float4*)(h + (size_t)base * IN_FEAT);
      float4* sd = (float4*)sh;
      const int cnt = nrows * (IN_FEAT / 4);
      for (int i = threadIdx.x; i < cnt; i += 256) sd[i] = hs[i];
    }
    __syncthreads();

    float4 acc[4];
    #pragma unroll
    for (int j = 0; j < 4; ++j) acc[j] = make_float4(0.f, 0.f, 0.f, 0.f);

    #pragma unroll 4
    for (int k = 0; k < IN_FEAT; ++k) {
      const float4 w = ((const float4*)slw)[k * 32 + cg_];
      #pragma unroll
      for (int j = 0; j < 4; ++j) {
        const float hv = sh[(rg + 8 * j) * IN_FEAT + k];
        acc[j].x += hv * w.x;
        acc[j].y += hv * w.y;
        acc[j].z += hv * w.z;
        acc[j].w += hv * w.w;
      }
    }

    #pragma unroll
    for (int j = 0; j < 4; ++j) {
      const int r = rg + 8 * j;
      if (r < nrows) {
        ((float4*)(out + (size_t)(base + r) * OUT_FEAT))[cg_] = acc[j];
      }
    }
  }
}

// ---------------------------------------------------------------------------
// f32 aggregation (middle fallback: ws fits sort but not bf16 buffers)
// ---------------------------------------------------------------------------
__global__ __launch_bounds__(256) void agg(
    const float* __restrict__ h, const float* __restrict__ norm,
    const float* __restrict__ weight, const int* __restrict__ pos,
    const int* __restrict__ cnt, const int2* __restrict__ srcet,
    float* __restrict__ out, int N) {
  const int node = (int)((blockIdx.x * blockDim.x + threadIdx.x) >> 6);
  const int lane = threadIdx.x & 63;
  if (node >= N) return;

  const int b = lane >> 2;
  const int op = (lane & 3) * 2;
  const int boff = b * 64 + op;

  const int num = cnt[node];
  const int end = pos[node];
  const int begin = end - num;

  float a0 = 0.f, a1 = 0.f;

  for (int base = 0; base < num; base += 64) {
    const int cn = min(64, num - base);
    const int2 my = srcet[begin + base + min(lane, cn - 1)];
    #pragma unroll 2
    for (int i = 0; i < cn; ++i) {
      const int s = __shfl(my.x, i);
      const int r = __shfl(my.y, i);
      const float* xp = h + ((size_t)s << 7) + b * 8;
      const float4 x0 = ((const float4*)xp)[0];
      const float4 x1 = ((const float4*)xp)[1];
      const float* wp = weight + ((size_t)r << 10) + boff;
      const float2 w0 = *(const float2*)(wp);
      const float2 w1 = *(const float2*)(wp + 8);
      const float2 w2 = *(const float2*)(wp + 16);
      const float2 w3 = *(const float2*)(wp + 24);
      const float2 w4 = *(const float2*)(wp + 32);
      const float2 w5 = *(const float2*)(wp + 40);
      const float2 w6 = *(const float2*)(wp + 48);
      const float2 w7 = *(const float2*)(wp + 56);
      a0 += x0.x * w0.x; a1 += x0.x * w0.y;
      a0 += x0.y * w1.x; a1 += x0.y * w1.y;
      a0 += x0.z * w2.x; a1 += x0.z * w2.y;
      a0 += x0.w * w3.x; a1 += x0.w * w3.y;
      a0 += x1.x * w4.x; a1 += x1.x * w4.y;
      a0 += x1.y * w5.x; a1 += x1.y * w5.y;
      a0 += x1.z * w6.x; a1 += x1.z * w6.y;
      a0 += x1.w * w7.x; a1 += x1.w * w7.y;
    }
  }

  const float nm = norm[node];
  const int o = b * 8 + op;
  float* outp = out + ((size_t)node << 7) + o;
  float2 prev = *(const float2*)outp;
  float2 res;
  res.x = fmaxf(prev.x + a0 * nm, 0.f);
  res.y = fmaxf(prev.y + a1 * nm, 0.f);
  *(float2*)outp = res;
}

// ---------------------------------------------------------------------------
// Last-resort fallback: per-edge atomics + separate relu.
// ---------------------------------------------------------------------------
__global__ __launch_bounds__(256) void edge_msg(
    const float* __restrict__ h, const float* __restrict__ norm,
    const float* __restrict__ weight, const int* __restrict__ src,
    const int* __restrict__ dst, const int* __restrict__ etype,
    float* out, int E) {
  const int wave = (int)((blockIdx.x * blockDim.x + threadIdx.x) >> 6);
  const int lane = threadIdx.x & 63;
  if (wave >= E) return;

  const int s = src[wave];
  const int d = dst[wave];
  const int r = etype[wave];
  const float nrm = norm[d];

  const int b = lane >> 2;
  const int op = (lane & 3) * 2;

  const float* xp = h + (size_t)s * IN_FEAT + b * 8;
  const float4 x0 = ((const float4*)xp)[0];
  const float4 x1 = ((const float4*)xp)[1];
  float x[8] = {x0.x, x0.y, x0.z, x0.w, x1.x, x1.y, x1.z, x1.w};

  const float* wp = weight + (size_t)r * 1024 + b * 64 + op;
  float a0 = 0.f, a1 = 0.f;
  #pragma unroll
  for (int i = 0; i < 8; ++i) {
    const float2 w = *(const float2*)(wp + i * 8);
    a0 += x[i] * w.x;
    a1 += x[i] * w.y;
  }

  const int o = b * 8 + op;
  float* outp = out + (size_t)d * OUT_FEAT + o;
  atomicAdd(outp, a0 * nrm);
  atomicAdd(outp + 1, a1 * nrm);
}

__global__ __launch_bounds__(256) void relu_k(float* __restrict__ out, int n4) {
  const int i = blockIdx.x * blockDim.x + threadIdx.x;
  if (i < n4) {
    float4 v = ((const float4*)out)[i];
    v.x = fmaxf(v.x, 0.f);
    v.y = fmaxf(v.y, 0.f);
    v.z = fmaxf(v.z, 0.f);
    v.w = fmaxf(v.w, 0.f);
    ((float4*)out)[i] = v;
  }
}

extern "C" void kernel_launch(void* const* d_in, const int* in_sizes, int n_in,
                              void* d_out, int out_size, void* d_ws, size_t ws_size,
                              hipStream_t stream) {
  const float* h    = (const float*)d_in[0];
  const float* norm = (const float*)d_in[1];
  const float* w    = (const float*)d_in[2];
  const float* lw   = (const float*)d_in[3];
  const int* src    = (const int*)d_in[4];
  const int* dst    = (const int*)d_in[5];
  const int* etype  = (const int*)d_in[6];
  float* out = (float*)d_out;

  const int N = in_sizes[1];            // norm has N elements
  const int E = in_sizes[4];            // src has E elements
  const int R = in_sizes[2] / 1024;     // weight rows
  const int nblk = (N + SCAN_CHUNK - 1) / SCAN_CHUNK;

  // ws layout: srcet[E] int2 | cnt[N] | pos[N] | bsum[max(nblk,128)] |
  //            h16[N*128] bf16 | w16[R*1024] bf16 | lwT[128*128] bf16
  const size_t nb_bsum = (size_t)((nblk < 128) ? 128 : nblk);
  const size_t off_cnt  = (size_t)E * 8;
  const size_t off_pos  = off_cnt + (size_t)N * 4;
  const size_t off_bsum = off_pos + (size_t)N * 4;
  size_t off_h16 = off_bsum + nb_bsum * 4;
  off_h16 = (off_h16 + 15) & ~(size_t)15;
  const size_t off_w16 = off_h16 + (size_t)N * IN_FEAT * 2;
  const size_t off_lwT = off_w16 + (size_t)R * 1024 * 2;
  const size_t need_full = off_lwT + (size_t)IN_FEAT * OUT_FEAT * 2;
  const size_t need_sort = off_bsum + nb_bsum * 4;

  if (ws_size >= need_full) {
    char* wsb = (char*)d_ws;
    int2* srcet = (int2*)wsb;
    int* cnt  = (int*)(wsb + off_cnt);
    int* pos  = (int*)(wsb + off_pos);
    int* bsum = (int*)(wsb + off_bsum);
    unsigned short* h16 = (unsigned short*)(wsb + off_h16);
    unsigned short* w16 = (unsigned short*)(wsb + off_w16);
    unsigned short* lwT = (unsigned short*)(wsb + off_lwT);

    hipMemsetAsync(cnt, 0, (size_t)N * 4, stream);

    // fused prologue: wpack (1 block/relation) + hpack + lwpack + hist (x4)
    const int htotal8 = N * IN_FEAT / 8;
    const int bw  = R;
    const int bh  = (htotal8 + 255) / 256;
    const int blw = (IN_FEAT * OUT_FEAT + 255) / 256;
    const int bhist = (E + 1023) / 1024;
    k_prep<<<bw + bh + blw + bhist, 256, 0, stream>>>(
        w, w16, h, (uint4*)h16, htotal8, lw, lwT, dst, cnt, E, bw, bh, blw);

    // fused: self-loop MFMA GEMM (out = loop_message) + chunk sums
    const int gemm_blocks = (N + 63) / 64;
    k_gemm_sum<<<gemm_blocks + nblk, 256, 0, stream>>>(
        h16, lwT, out, N, cnt, bsum, gemm_blocks);

    // offsets (inline bsum prefix) + scatter (4 edges/thread)
    k_offsets<<<nblk, 256, 0, stream>>>(cnt, bsum, pos, N);
    k_scatter<<<(E + 1023) / 1024, 256, 0, stream>>>(src, dst, etype, pos,
                                                     srcet, E);

    // one wave per node; fused norm + self-loop add + relu
    agg_bf16<<<(N + 3) / 4, 256, 0, stream>>>(h16, norm, w16, pos, cnt, srcet,
                                              out, N);
  } else if (ws_size >= need_sort) {
    char* wsb = (char*)d_ws;
    int2* srcet = (int2*)wsb;
    int* cnt  = (int*)(wsb + off_cnt);
    int* pos  = (int*)(wsb + off_pos);
    int* bsum = (int*)(wsb + off_bsum);

    selfloop_gemm<<<512, 256, 0, stream>>>(h, lw, out, N);
    hipMemsetAsync(cnt, 0, (size_t)N * 4, stream);
    k_hist<<<(E + 255) / 256, 256, 0, stream>>>(dst, cnt, E);
    k_chunksum<<<nblk, 256, 0, stream>>>(cnt, bsum, N);
    k_offsets<<<nblk, 256, 0, stream>>>(cnt, bsum, pos, N);
    k_scatter<<<(E + 1023) / 1024, 256, 0, stream>>>(src, dst, etype, pos,
                                                     srcet, E);
    agg<<<(N + 3) / 4, 256, 0, stream>>>(h, norm, w, pos, cnt, srcet, out, N);
  } else {
    selfloop_gemm<<<512, 256, 0, stream>>>(h, lw, out, N);
    edge_msg<<<(E + 3) / 4, 256, 0, stream>>>(h, norm, w, src, dst, etype, out, E);
    const int n4 = N * OUT_FEAT / 4;
    relu_k<<<(n4 + 255) / 256, 256, 0, stream>>>(out, n4);
  }
}